// Round 6
// baseline (157.773 us; speedup 1.0000x reference)
//
#include <hip/hip_runtime.h>
#include <math.h>

#define L_LEN 16384
#define M_LEN 8192
#define KT_LEN 4096
#define BB 32
#define NTPL 50
#define SPEC_STRIDE 8224   // complex slots per signal (>= 8193)
#define NSIG 166           // 64 x-signals + 2 w-signals + 100 templates
#define NTF 1024           // fwd block (radix-8 ladder, latency-bound regime)
#define NTI 512            // inv block (radix-16 ladder, issue-bound regime)
#define PI_F 3.14159265358979323846f
// cos/sin(pi/16): inv stage-3 twiddle base (radix-16 ladder)
#define C16 0.98078528040323044f
#define S16 0.19509032201612827f
// cos/sin(2*pi/16): fwd stage-4 twiddle base (radix-8 ladder)
#define C8 0.92387953251128674f
#define S8 0.38268343236508978f

typedef float cf2 __attribute__((ext_vector_type(2)));

// Lessons encoded in this structure:
//  R5: scattered per-lane twiddle table loads stall VMEM -> power chain from 1 load.
//  R6: XOR swizzle + cf2 packed math + algebraic per-stage indices = best layout.
//  R7: +1-per-32 pad layout TRIPLES bank conflicts vs XOR swizzle (FFT tiles).
//  R8: __shfl_xor compiles to ds_bpermute (LDS pipe!) - generic shfl-based
//      stage fusion is slower than plain LDS stages. Explicit DPP (VALU pipe)
//      is the exception - see R14.
//  R9: radix-8/1024-thr doubled occupancy (36->72%) but VALUBusy stayed ~74%
//      and dur rose 69->75us. inv is ISSUE-bound, not occupancy-bound:
//      radix-16 @512 for inv; fwd (1 block/CU, latency-bound) keeps 1024-thr radix-8.
//  R10: cmul via VOP3P pk asm: VALUBusy 74->64%, inv 69->67.5us. Packed math
//      is the right lever; compiler does NOT form op_sel broadcasts itself.
//  R11: pk-ified product/untangle pass: VALU 64->58.6%, inv 67.5->65.2us.
//  R12: head LDS-staged + unrolled: total unchanged -> head was never the
//      residual. Residual (total - inv ~87us) ~= fwd (15-25) + harness overhead.
//  R13 REVERTED: pair-based fwd untangle fixed LDS read conflicts but broke
//      global write coalescing (stride-512B lane scatter) -> total +4.7us.
//      Keep the coalesced-writes untangle even though reads are conflicted.
//  R14 (this round): inv stage-3 + final radix-2 + max fused via DPP
//      quad_perm[1,0,3,2] lane swap (VALU pipe, not LDS). Thread pair
//      (j=0,j=1) holds even/odd of each radix-2 pair in matching regs.
//      j=1's (own-partner) = -R_o is excluded from the max (one select).
//      Removes 16 ds_write_b64 + 8 ds_read_b128 + 1 barrier per thread.

// Packed complex multiply: 2 VOP3P instructions.
__device__ __forceinline__ cf2 cmul(cf2 a, cf2 b) {
    cf2 t, d;
    asm("v_pk_mul_f32 %0, %1, %2 op_sel:[0,0] op_sel_hi:[0,1]"
        : "=v"(t) : "v"(a), "v"(b));
    asm("v_pk_fma_f32 %0, %1, %2, %3 op_sel:[1,1,0] op_sel_hi:[1,0,1] neg_lo:[0,1,0]"
        : "=v"(d) : "v"(a), "v"(b), "v"(t));
    return d;
}
// a * conj(b): re = ax*bx + ay*by, im = ay*bx - ax*by. 2 VOP3P insts.
__device__ __forceinline__ cf2 cmulc(cf2 a, cf2 b) {
    cf2 t, d;
    asm("v_pk_mul_f32 %0, %1, %2 op_sel:[0,0] op_sel_hi:[0,1] neg_hi:[0,1]"
        : "=v"(t) : "v"(a), "v"(b));   // {ax*bx, -ax*by}
    asm("v_pk_fma_f32 %0, %1, %2, %3 op_sel:[1,1,0] op_sel_hi:[1,0,1]"
        : "=v"(d) : "v"(a), "v"(b), "v"(t));
    return d;
}
// conj(a) * b: re = ax*bx + ay*by, im = ax*by - ay*bx. 2 VOP3P insts.
__device__ __forceinline__ cf2 cmulca(cf2 a, cf2 b) {
    cf2 t, d;
    asm("v_pk_mul_f32 %0, %1, %2 op_sel:[0,0] op_sel_hi:[0,1]"
        : "=v"(t) : "v"(a), "v"(b));   // {ax*bx, ax*by}
    asm("v_pk_fma_f32 %0, %1, %2, %3 op_sel:[1,1,0] op_sel_hi:[1,0,1] neg_hi:[1,0,0]"
        : "=v"(d) : "v"(a), "v"(b), "v"(t));
    return d;
}
// {ax+bx, ay-by}
__device__ __forceinline__ cf2 pk_addch(cf2 a, cf2 b) {
    cf2 d;
    asm("v_pk_add_f32 %0, %1, %2 neg_hi:[0,1]" : "=v"(d) : "v"(a), "v"(b));
    return d;
}
// {ax-bx, ay+by}
__device__ __forceinline__ cf2 pk_subcl(cf2 a, cf2 b) {
    cf2 d;
    asm("v_pk_add_f32 %0, %1, %2 neg_lo:[0,1]" : "=v"(d) : "v"(a), "v"(b));
    return d;
}
// {s.x - r.y, s.y + r.x}  (= s + i*r)
__device__ __forceinline__ cf2 pk_compose1(cf2 s, cf2 r) {
    cf2 d;
    asm("v_pk_add_f32 %0, %1, %2 op_sel:[0,1] op_sel_hi:[0,0] neg_lo:[0,1]"
        : "=v"(d) : "v"(s), "v"(r));
    return d;
}
// {s.x + r.y, r.x - s.y}  (= conj(s - i*r))
__device__ __forceinline__ cf2 pk_compose2(cf2 s, cf2 r) {
    cf2 d;
    asm("v_pk_add_f32 %0, %1, %2 op_sel:[0,1] op_sel_hi:[0,0] neg_hi:[1,0]"
        : "=v"(d) : "v"(s), "v"(r));
    return d;
}
// Swap adjacent lanes (0<->1, 2<->3, ...) via DPP quad_perm[1,0,3,2] = 0xB1.
// VALU pipe - does NOT touch LDS (unlike __shfl_xor -> ds_bpermute, R8).
__device__ __forceinline__ float dpp_swap1(float x) {
    return __int_as_float(
        __builtin_amdgcn_mov_dpp(__float_as_int(x), 0xB1, 0xF, 0xF, true));
}
template<int SIGN>
__device__ __forceinline__ cf2 rot90(cf2 z) {
    return (SIGN < 0) ? (cf2){z.y, -z.x} : (cf2){-z.y, z.x};
}
template<int SIGN>
__device__ __forceinline__ cf2 ldT(const cf2* __restrict__ T, int idx) {
    cf2 t = T[idx];
    if (SIGN > 0) t.y = -t.y;
    return t;
}

// LDS bank swizzle. Even XOR keeps float4 pair adjacency; involution.
__device__ __forceinline__ int swz(int i) { return i ^ (((i >> 5) & 15) << 1); }

// Digit reversal for fwd's radix 8,8,8,8,2 DIF ladder.
__device__ __forceinline__ int pos8(int f) {
    return ((f & 7) << 10) | (((f >> 3) & 7) << 7) |
           (((f >> 6) & 7) << 4) | (((f >> 9) & 7) << 1) | ((f >> 12) & 1);
}

// ---------------- radix-16 pieces (inv kernel) ----------------
template<int SIGN>
__device__ __forceinline__ void dft16(cf2 x[16]) {
    const float S = (SIGN < 0) ? -1.f : 1.f;
    const cf2 w1 = {0.9238795325112867f, S * 0.3826834323650898f};
    const cf2 w2 = {0.7071067811865476f, S * 0.7071067811865476f};
    const cf2 w3 = {0.3826834323650898f, S * 0.9238795325112867f};
    cf2 v[16];
    #pragma unroll
    for (int n1 = 0; n1 < 4; ++n1) {
        cf2 a0 = x[n1], a1 = x[n1+4], a2 = x[n1+8], a3 = x[n1+12];
        cf2 t0 = a0 + a2, t2 = a0 - a2;
        cf2 t1 = a1 + a3, t3 = rot90<SIGN>(a1 - a3);
        cf2 u0 = t0 + t1, u1 = t2 + t3;
        cf2 u2 = t0 - t1, u3 = t2 - t3;
        if (n1 == 1) { u1 = cmul(u1, w1); u2 = cmul(u2, w2); u3 = cmul(u3, w3); }
        else if (n1 == 2) { u1 = cmul(u1, w2); u2 = rot90<SIGN>(u2);
                            u3 = rot90<SIGN>(cmul(u3, w2)); }
        else if (n1 == 3) { u1 = cmul(u1, w3); u2 = rot90<SIGN>(cmul(u2, w2));
                            u3 = -cmul(u3, w1); }
        v[0*4+n1] = u0; v[1*4+n1] = u1; v[2*4+n1] = u2; v[3*4+n1] = u3;
    }
    #pragma unroll
    for (int r = 0; r < 4; ++r) {
        cf2 a0 = v[r*4+0], a1 = v[r*4+1], a2 = v[r*4+2], a3 = v[r*4+3];
        cf2 t0 = a0 + a2, t2 = a0 - a2;
        cf2 t1 = a1 + a3, t3 = rot90<SIGN>(a1 - a3);
        x[r]    = t0 + t1; x[r+4]  = t2 + t3;
        x[r+8]  = t0 - t1; x[r+12] = t2 - t3;
    }
}

template<int SIGN>
__device__ __forceinline__ void butterfly16(cf2* A, const int idx[16], cf2 w1) {
    cf2 x[16];
    #pragma unroll
    for (int n = 0; n < 16; ++n) x[n] = A[idx[n]];
    dft16<SIGN>(x);
    A[idx[0]] = x[0];
    A[idx[1]] = cmul(x[1], w1);
    const cf2 w2 = cmul(w1, w1);
    A[idx[2]] = cmul(x[2], w2);
    const cf2 w3 = cmul(w1, w2);
    A[idx[3]] = cmul(x[3], w3);
    const cf2 w4 = cmul(w2, w2);
    A[idx[4]] = cmul(x[4], w4);
    A[idx[5]] = cmul(x[5], cmul(w1, w4));
    A[idx[6]] = cmul(x[6], cmul(w2, w4));
    A[idx[7]] = cmul(x[7], cmul(w3, w4));
    const cf2 w8 = cmul(w4, w4);
    A[idx[8]]  = cmul(x[8],  w8);
    A[idx[9]]  = cmul(x[9],  cmul(w1, w8));
    A[idx[10]] = cmul(x[10], cmul(w2, w8));
    A[idx[11]] = cmul(x[11], cmul(w3, w8));
    const cf2 w12 = cmul(w4, w8);
    A[idx[12]] = cmul(x[12], w12);
    A[idx[13]] = cmul(x[13], cmul(w1, w12));
    A[idx[14]] = cmul(x[14], cmul(w2, w12));
    A[idx[15]] = cmul(x[15], cmul(w3, w12));
}

// ---------------- radix-8 pieces (fwd kernel) ----------------
template<int SIGN>
__device__ __forceinline__ void dft8(cf2 x[8]) {
    const float R2 = 0.70710678118654752f;
    const cf2 w81 = { R2, SIGN * R2 };
    const cf2 w83 = { -R2, SIGN * R2 };
    cf2 u0 = x[0] + x[4], u1 = x[1] + x[5], u2 = x[2] + x[6], u3 = x[3] + x[7];
    cf2 v0 = x[0] - x[4];
    cf2 v1 = cmul(x[1] - x[5], w81);
    cf2 v2 = rot90<SIGN>(x[2] - x[6]);
    cf2 v3 = cmul(x[3] - x[7], w83);
    cf2 t0 = u0 + u2, t2 = u0 - u2;
    cf2 t1 = u1 + u3, t3 = rot90<SIGN>(u1 - u3);
    x[0] = t0 + t1; x[2] = t2 + t3; x[4] = t0 - t1; x[6] = t2 - t3;
    cf2 s0 = v0 + v2, s2 = v0 - v2;
    cf2 s1 = v1 + v3, s3 = rot90<SIGN>(v1 - v3);
    x[1] = s0 + s1; x[3] = s2 + s3; x[5] = s0 - s1; x[7] = s2 - s3;
}

template<int SIGN>
__device__ __forceinline__ void butterfly8(cf2* A, const int idx[8], cf2 w1) {
    cf2 x[8];
    #pragma unroll
    for (int n = 0; n < 8; ++n) x[n] = A[idx[n]];
    dft8<SIGN>(x);
    A[idx[0]] = x[0];
    A[idx[1]] = cmul(x[1], w1);
    const cf2 w2 = cmul(w1, w1);
    A[idx[2]] = cmul(x[2], w2);
    const cf2 w3 = cmul(w1, w2);
    A[idx[3]] = cmul(x[3], w3);
    const cf2 w4 = cmul(w2, w2);
    A[idx[4]] = cmul(x[4], w4);
    A[idx[5]] = cmul(x[5], cmul(w1, w4));
    A[idx[6]] = cmul(x[6], cmul(w2, w4));
    A[idx[7]] = cmul(x[7], cmul(w3, w4));
}

// ---------------------------------------------------------------------------
// Kernel 1: forward real FFT (length 16384) via 8192-pt complex FFT.
// Radix 8,8,8,8,2 ladder, 1024 threads (R9). Blocks [NSIG, NSIG+16) build the
// twiddle table T via quadrant-reduced float sincos. W blocks (sig 64/65)
// write V(f) = conj(W(f)) * e^{-i pi k/8192}, k = 4094*f mod 16384.
// Untangle: R4 form (coalesced out[f] writes; R13's pair variant regressed).
// ---------------------------------------------------------------------------
__global__ __launch_bounds__(NTF, 4)
void fwd_fft_kernel(const float* __restrict__ xi, const float* __restrict__ w,
                    const float* __restrict__ tmpl, cf2* __restrict__ Tw,
                    cf2* __restrict__ spec) {
    __shared__ __attribute__((aligned(16))) cf2 A[M_LEN];   // 64 KB
    const int sig = blockIdx.x;
    const int tid = threadIdx.x;

    if (sig >= NSIG) {   // twiddle writer: T[k] = e^{-2 pi i k / 16384}
        const int k = (sig - NSIG) * NTF + tid;
        const int quad = k >> 12, mm = k & 4095;
        float s, c; __sincosf(PI_F * (float)mm / 8192.f, &s, &c);
        cf2 v;   // (cos th, -sin th), th = pi k/8192 = quad*pi/2 + t
        if      (quad == 0) v = (cf2){ c, -s};
        else if (quad == 1) v = (cf2){-s, -c};
        else if (quad == 2) v = (cf2){-c,  s};
        else                v = (cf2){ s,  c};
        Tw[k] = v;
        return;
    }

    const float* src;
    int nre;
    if (sig < 64)      { src = xi   + sig * L_LEN;         nre = L_LEN; }
    else if (sig < 66) { src = w    + (sig - 64) * L_LEN;  nre = L_LEN; }
    else               { src = tmpl + (sig - 66) * KT_LEN; nre = KT_LEN; }
    const bool isW = (sig >= 64 && sig < 66);
    const int nc = nre >> 1;
    const float4* s4 = (const float4*)src;
    const int g0 = tid ^ ((tid >> 4) & 15);
    #pragma unroll
    for (int m = 0; m < 4; ++m) {
        const int u = 2*tid + 2048*m;
        float4 vv = (u < nc) ? s4[tid + 1024*m] : make_float4(0.f, 0.f, 0.f, 0.f);
        ((float4*)A)[g0 + 1024*m] = vv;
    }
    __syncthreads();

    {   // stage 1: stride 1024, w1 = W_8192^tid
        int idx[8]; const int b0 = swz(tid);
        #pragma unroll
        for (int n = 0; n < 8; ++n) idx[n] = b0 + 1024*n;
        float sn, cs; __sincosf(-PI_F * (float)(2*tid) / 8192.f, &sn, &cs);
        butterfly8<-1>(A, idx, (cf2){cs, sn});
    }
    __syncthreads();
    {   // stage 2: stride 128, w1 = W_1024^j
        const int blk = tid >> 7, j = tid & 127, jb = blk*1024;
        const int jsw = j ^ (((j >> 5) & 3) << 1);
        int idx[8];
        #pragma unroll
        for (int n = 0; n < 8; ++n) idx[n] = jb + 128*n + (jsw ^ ((n & 3) << 3));
        float sn, cs; __sincosf(-PI_F * (float)(16*j) / 8192.f, &sn, &cs);
        butterfly8<-1>(A, idx, (cf2){cs, sn});
    }
    __syncthreads();
    {   // stage 3: stride 16, w1 = W_128^j
        const int blk = tid >> 4, j = tid & 15;
        const int base = blk*128 + j, bx = (blk & 3) << 3;
        int idx[8];
        #pragma unroll
        for (int n = 0; n < 8; ++n) idx[n] = (base + 16*n) ^ bx ^ ((n >> 1) << 1);
        float sn, cs; __sincosf(-PI_F * (float)(128*j) / 8192.f, &sn, &cs);
        butterfly8<-1>(A, idx, (cf2){cs, sn});
    }
    __syncthreads();
    {   // stage 4: stride 2, w1 = W_16^j (constant)
        const int blk = tid >> 1, j = tid & 1;
        const int Xa = ((blk >> 1) & 15) << 1;
        const int base = ((blk << 4) | j) ^ (Xa & 16);
        const int xv = Xa & 14;
        int idx[8];
        #pragma unroll
        for (int n = 0; n < 8; ++n) idx[n] = base + ((2*n) ^ xv);
        cf2 w1 = j ? (cf2){C8, -S8} : (cf2){1.f, 0.f};
        butterfly8<-1>(A, idx, w1);
    }
    __syncthreads();
    // Final radix-2 (stride 1, no twiddle), b128 in-place.
    #pragma unroll
    for (int m = 0; m < 4; ++m) {
        float4 pq = ((float4*)A)[g0 + 1024*m];
        ((float4*)A)[g0 + 1024*m] = make_float4(pq.x + pq.z, pq.y + pq.w,
                                                pq.x - pq.z, pq.y - pq.w);
    }
    __syncthreads();

    // Untangle packed result to real-signal spectrum X[f], f = 0..M.
    cf2* out = spec + (size_t)sig * SPEC_STRIDE;
    #pragma unroll
    for (int m = 0; m < 8; ++m) {
        const int f = tid + 1024*m;
        const int fb = (M_LEN - f) & (M_LEN - 1);
        cf2 Za = A[swz(pos8(f))];
        cf2 Zb = A[swz(pos8(fb))];
        cf2 E = (cf2){0.5f*(Za.x + Zb.x), 0.5f*(Za.y - Zb.y)};
        cf2 D = (cf2){Za.x - Zb.x, Za.y + Zb.y};
        cf2 O = (cf2){0.5f*D.y, -0.5f*D.x};
        float sn, cs;
        __sincosf(-PI_F * (float)f / 8192.f, &sn, &cs);
        cf2 val = E + (cf2){cs*O.x - sn*O.y, cs*O.y + sn*O.x};
        if (isW) {   // V(f) = conj(W(f)) * e^{-i pi k/8192}, k exact int mod
            const int k = (4094 * f) & (L_LEN - 1);
            float psn, pcs; __sincosf(-PI_F * (float)k / 8192.f, &psn, &pcs);
            val = cmul((cf2){val.x, -val.y}, (cf2){pcs, psn});
        }
        out[f] = val;
    }
    if (tid == 0) {   // f = 8192
        cf2 Za = A[swz(0)];
        cf2 val = (cf2){Za.x - Za.y, 0.f};
        if (isW) {   // k(8192) = 8192 -> phase = (-1, 0)
            val = (cf2){-val.x, 0.f};
        }
        out[M_LEN] = val;
    }
}

// ---------------------------------------------------------------------------
// Kernel 2: per (b,n,c): S[f] = X[f]*V[f]*conj(H[f]); Hermitian pack fused
// into the product pass (fully VOP3P-packed, R11; 2x scale folded into the
// final divide); 2 radix-16 LDS stages; stage 3 + final radix-2 + max fused
// in registers via DPP lane swap (R14).
// ---------------------------------------------------------------------------
__global__ __launch_bounds__(NTI, 4)
void inv_fft_kernel(const cf2* __restrict__ spec, const cf2* __restrict__ T,
                    const float* __restrict__ hh, float* __restrict__ zarr) {
    __shared__ __attribute__((aligned(16))) cf2 A[M_LEN];   // 64 KB
    const int idx0 = blockIdx.x;
    const int c = idx0 & 1;
    const int n = (idx0 >> 1) % NTPL;
    const int b = idx0 / (2 * NTPL);
    const int tid = threadIdx.x;

    const cf2* Xs = spec + (size_t)(b*2 + c)      * SPEC_STRIDE;
    const cf2* Vs = spec + (size_t)(64 + c)       * SPEC_STRIDE;
    const cf2* Hs = spec + (size_t)(66 + n*2 + c) * SPEC_STRIDE;
    const float4* X4 = (const float4*)Xs;
    const float4* V4 = (const float4*)Vs;
    const float4* H4 = (const float4*)Hs;
    const float4* T4 = (const float4*)T;
    const int g0 = tid ^ ((tid >> 4) & 15);

    // Fused product + Hermitian pack, all VOP3P. Thread t handles f =
    // 2t+1024m+{0,1} (f in [0,4096)) and partners 8192-f. Writes all of
    // Z'[0..8191] with a uniform 2x scale (0.5 dropped; f=4096 doubled;
    // final zarr divide uses 2*M_LEN).
    #pragma unroll
    for (int m = 0; m < 4; ++m) {
        const int u = 2*tid + 1024*m;
        float4 xf = X4[tid + 512*m], vf = V4[tid + 512*m], hf = H4[tid + 512*m];
        cf2 P0 = cmulc(cmul((cf2){xf.x, xf.y}, (cf2){vf.x, vf.y}), (cf2){hf.x, hf.y});
        cf2 P1 = cmulc(cmul((cf2){xf.z, xf.w}, (cf2){vf.z, vf.w}), (cf2){hf.z, hf.w});
        cf2 Q0 = cmulc(cmul(Xs[M_LEN - u],     Vs[M_LEN - u]),     Hs[M_LEN - u]);
        cf2 Q1 = cmulc(cmul(Xs[M_LEN - 1 - u], Vs[M_LEN - 1 - u]), Hs[M_LEN - 1 - u]);
        float4 tw = T4[tid + 512*m];          // T[u], T[u+1]
        cf2 t0 = (cf2){tw.x, tw.y}, t1 = (cf2){tw.z, tw.w};
        cf2 Sp0 = pk_addch(P0, Q0), Sm0 = pk_subcl(P0, Q0);
        cf2 R0 = cmulca(t0, Sm0);
        cf2 Sp1 = pk_addch(P1, Q1), Sm1 = pk_subcl(P1, Q1);
        cf2 R1 = cmulca(t1, Sm1);
        cf2 Z0 = pk_compose1(Sp0, R0);        // Z'[u]     = Sp + i*R
        cf2 Z1 = pk_compose1(Sp1, R1);
        ((float4*)A)[g0 + 512*m] = make_float4(Z0.x, Z0.y, Z1.x, Z1.y);
        if (u > 0) A[swz(M_LEN - u)] = pk_compose2(Sp0, R0);  // conj(Sp - i*R)
        A[swz(M_LEN - 1 - u)] = pk_compose2(Sp1, R1);
    }
    if (tid == 0) {   // f = 4096 (self-paired), doubled to match the 2x scale
        cf2 S = cmulc(cmul(Xs[4096], Vs[4096]), Hs[4096]);
        A[swz(4096)] = (cf2){2.f * S.x, -2.f * S.y};
    }
    __syncthreads();

    {   // stage 1: stride 512, es = 2*tid
        int idx[16]; const int b0 = swz(tid);
        #pragma unroll
        for (int nn = 0; nn < 16; ++nn) idx[nn] = b0 + 512*nn;
        butterfly16<+1>(A, idx, ldT<+1>(T, 2*tid));
    }
    __syncthreads();
    {   // stage 2: stride 32, es = 32*j
        const int blk = tid >> 5, j = tid & 31, jb = blk*512;
        int idx[16];
        #pragma unroll
        for (int nn = 0; nn < 16; ++nn) idx[nn] = jb + 32*nn + (j ^ (2*nn));
        butterfly16<+1>(A, idx, ldT<+1>(T, 32*j));
    }
    __syncthreads();

    // Stage 3 (stride 2) fused with the final radix-2 and the max (R14).
    // Lane pair (tid even: j=0, tid odd: j=1, same blk) holds the even/odd
    // element of every radix-2 pair in matching register slots x[nn]:
    //   j=0: offset (2nn)^xv (even);  j=1: offset (2nn)^xv + 1 (odd).
    // After twiddling: R_e = E+O, R_o = E-O. DPP swap gives each lane the
    // partner. j=1's (own-partner) = -R_o is excluded from the max.
    float mx;
    {
        const int blk = tid >> 1, j = tid & 1;
        const int xv = (blk & 15) << 1, b3 = blk*32 + j;
        cf2 x[16];
        #pragma unroll
        for (int nn = 0; nn < 16; ++nn) x[nn] = A[b3 + ((2*nn) ^ xv)];
        dft16<+1>(x);
        cf2 w1 = j ? (cf2){C16, S16} : (cf2){1.f, 0.f};
        // twiddle chain (same as butterfly16's store-side twiddles)
        x[1] = cmul(x[1], w1);
        const cf2 w2 = cmul(w1, w1);
        x[2] = cmul(x[2], w2);
        const cf2 w3 = cmul(w1, w2);
        x[3] = cmul(x[3], w3);
        const cf2 w4 = cmul(w2, w2);
        x[4] = cmul(x[4], w4);
        x[5] = cmul(x[5], cmul(w1, w4));
        x[6] = cmul(x[6], cmul(w2, w4));
        x[7] = cmul(x[7], cmul(w3, w4));
        const cf2 w8 = cmul(w4, w4);
        x[8]  = cmul(x[8],  w8);
        x[9]  = cmul(x[9],  cmul(w1, w8));
        x[10] = cmul(x[10], cmul(w2, w8));
        x[11] = cmul(x[11], cmul(w3, w8));
        const cf2 w12 = cmul(w4, w8);
        x[12] = cmul(x[12], w12);
        x[13] = cmul(x[13], cmul(w1, w12));
        x[14] = cmul(x[14], cmul(w2, w12));
        x[15] = cmul(x[15], cmul(w3, w12));
        float mxs = -INFINITY, mxd = -INFINITY;
        #pragma unroll
        for (int nn = 0; nn < 16; ++nn) {
            cf2 p = (cf2){dpp_swap1(x[nn].x), dpp_swap1(x[nn].y)};
            cf2 s = x[nn] + p;     // R_e (both lanes)
            cf2 d = x[nn] - p;     // j=0: R_o;  j=1: -R_o (excluded)
            mxs = fmaxf(mxs, fmaxf(s.x, s.y));
            mxd = fmaxf(mxd, fmaxf(d.x, d.y));
        }
        mx = j ? mxs : fmaxf(mxs, mxd);
    }
    __syncthreads();   // all stage-3 reads of A done before reusing as scratch
    for (int off = 32; off > 0; off >>= 1)
        mx = fmaxf(mx, __shfl_xor(mx, off));
    const int lane = tid & 63, wv = tid >> 6;   // 8 waves
    float* redf = (float*)A;
    if (lane == 0) redf[wv] = mx;
    __syncthreads();
    if (tid == 0) {
        float mm = redf[0];
        for (int i = 1; i < NTI/64; ++i) mm = fmaxf(mm, redf[i]);
        zarr[(b*2 + c)*NTPL + n] = mm / (2.f * (float)M_LEN * hh[n*2 + c]);
    }
}

// ---------------------------------------------------------------------------
// Kernel 3: tiny CNN/MLP head. One block per batch element.
// R12: all weights staged in LDS (coalesced), all MAC loops unrolled over
// LDS reads, fc1 parallelized 32 outputs x 8 lanes + shfl_xor tree.
// ---------------------------------------------------------------------------
#define W1_OFF 0        // 16x6 = 96
#define B1_OFF 96       // 16
#define W2_OFF 112      // 32x48 = 1536
#define B2_OFF 1648     // 32
#define W3_OFF 1680     // 32x132 (padded from 128) = 4224
#define B3_OFF 5904     // 32
#define W4_OFF 5936     // 2x32 = 64
#define B4_OFF 6000     // 2
#define WSM_SZ 6002

__global__ __launch_bounds__(256)
void head_kernel(const float* __restrict__ zarr,
                 const float* __restrict__ W1, const float* __restrict__ b1,
                 const float* __restrict__ W2, const float* __restrict__ b2,
                 const float* __restrict__ W3, const float* __restrict__ b3,
                 const float* __restrict__ W4, const float* __restrict__ b4,
                 float* __restrict__ out) {
    __shared__ float wsm[WSM_SZ];
    __shared__ float zl[2*NTPL];
    __shared__ float s1[16*48];
    __shared__ float p1[16*16];
    __shared__ float s2[32*14];
    __shared__ float hflat[128];
    __shared__ float h1[32];
    const int b = blockIdx.x, tid = threadIdx.x;

    // Cooperative weight staging (coalesced global reads).
    for (int i = tid; i < 96;   i += 256) wsm[W1_OFF + i] = W1[i];
    if (tid < 16)                         wsm[B1_OFF + tid] = b1[tid];
    for (int i = tid; i < 1536; i += 256) wsm[W2_OFF + i] = W2[i];
    if (tid < 32)                         wsm[B2_OFF + tid] = b2[tid];
    for (int i = tid; i < 4096; i += 256)
        wsm[W3_OFF + (i >> 7)*132 + (i & 127)] = W3[i];
    if (tid < 32)                         wsm[B3_OFF + tid] = b3[tid];
    if (tid < 64)                         wsm[W4_OFF + tid] = W4[tid];
    if (tid < 2)                          wsm[B4_OFF + tid] = b4[tid];
    for (int i = tid; i < 2*NTPL; i += 256) zl[i] = zarr[b*2*NTPL + i];
    __syncthreads();

    // conv1 + sigmoid: 16 ch x 48 t
    for (int i = tid; i < 16*48; i += 256) {
        const int o = i / 48, t = i % 48;
        float acc = wsm[B1_OFF + o];
        #pragma unroll
        for (int cc = 0; cc < 2; ++cc)
            #pragma unroll
            for (int k = 0; k < 3; ++k)
                acc += zl[cc*NTPL + t + k] * wsm[W1_OFF + o*6 + cc*3 + k];
        s1[i] = 1.f / (1.f + __expf(-acc));
    }
    __syncthreads();
    // pool1: 16 x 16
    for (int i = tid; i < 16*16; i += 256) {
        const int o = i / 16, u = i % 16;
        p1[i] = fmaxf(fmaxf(s1[o*48 + 3*u], s1[o*48 + 3*u+1]), s1[o*48 + 3*u+2]);
    }
    __syncthreads();
    // conv2 + sigmoid: 32 ch x 14 t (fully unrolled, LDS reads only)
    for (int i = tid; i < 32*14; i += 256) {
        const int o = i / 14, t = i % 14;
        float acc = wsm[B2_OFF + o];
        #pragma unroll
        for (int cc = 0; cc < 16; ++cc)
            #pragma unroll
            for (int k = 0; k < 3; ++k)
                acc += p1[cc*16 + t + k] * wsm[W2_OFF + o*48 + cc*3 + k];
        s2[o*14 + t] = 1.f / (1.f + __expf(-acc));
    }
    __syncthreads();
    // pool2 -> hflat[128]
    for (int i = tid; i < 128; i += 256) {
        const int o = i / 4, u = i % 4;
        hflat[i] = fmaxf(fmaxf(s2[o*14 + 3*u], s2[o*14 + 3*u+1]), s2[o*14 + 3*u+2]);
    }
    __syncthreads();
    // fc1 + relu: 32 outputs x 8 lanes each, shfl_xor tree reduce.
    {
        const int o = tid >> 3, lg = tid & 7;
        float acc = 0.f;
        #pragma unroll
        for (int k = 0; k < 16; ++k)
            acc += hflat[lg + 8*k] * wsm[W3_OFF + o*132 + lg + 8*k];
        acc += __shfl_xor(acc, 1);
        acc += __shfl_xor(acc, 2);
        acc += __shfl_xor(acc, 4);
        if (lg == 0) h1[o] = fmaxf(acc + wsm[B3_OFF + o], 0.f);
    }
    __syncthreads();
    // fc2: 2 outputs x 32 lanes, shfl_xor tree (masks <32 keep halves apart).
    if (tid < 64) {
        const int o = tid >> 5, j = tid & 31;
        float p = h1[j] * wsm[W4_OFF + o*32 + j];
        p += __shfl_xor(p, 1);
        p += __shfl_xor(p, 2);
        p += __shfl_xor(p, 4);
        p += __shfl_xor(p, 8);
        p += __shfl_xor(p, 16);
        if (j == 0) out[b*2 + o] = p + wsm[B4_OFF + o];
    }
}

extern "C" void kernel_launch(void* const* d_in, const int* in_sizes, int n_in,
                              void* d_out, int out_size, void* d_ws, size_t ws_size,
                              hipStream_t stream) {
    const float* xi   = (const float*)d_in[0];
    const float* Sw   = (const float*)d_in[1];
    const float* tmpl = (const float*)d_in[2];
    const float* hh   = (const float*)d_in[3];
    const float* W1   = (const float*)d_in[4];
    const float* b1   = (const float*)d_in[5];
    const float* W2   = (const float*)d_in[6];
    const float* b2   = (const float*)d_in[7];
    const float* W3   = (const float*)d_in[8];
    const float* b3   = (const float*)d_in[9];
    const float* W4   = (const float*)d_in[10];
    const float* b4   = (const float*)d_in[11];
    float* out = (float*)d_out;

    cf2* T16  = (cf2*)d_ws;                         // 16384 cf2 = 128 KB
    cf2* spec = T16 + 16384;                        // NSIG * SPEC_STRIDE cf2
    float* zarr = (float*)(spec + (size_t)NSIG * SPEC_STRIDE);

    // fwd grid: NSIG FFT blocks + 16 twiddle-table writer blocks (NTF=1024).
    // W blocks write V = conj(W)*phase, so no premul kernel is needed.
    fwd_fft_kernel<<<dim3(NSIG + 16), dim3(NTF), 0, stream>>>(xi, Sw, tmpl, T16, spec);
    inv_fft_kernel<<<dim3(BB * NTPL * 2), dim3(NTI), 0, stream>>>(spec, T16, hh, zarr);
    head_kernel<<<dim3(BB), dim3(256), 0, stream>>>(zarr, W1, b1, W2, b2, W3, b3, W4, b4, out);
}

// Round 7
// 154.542 us; speedup vs baseline: 1.0209x; 1.0209x over previous
//
#include <hip/hip_runtime.h>
#include <math.h>

#define L_LEN 16384
#define M_LEN 8192
#define KT_LEN 4096
#define BB 32
#define NTPL 50
#define SPEC_STRIDE 8224   // complex slots per signal (>= 8193)
#define NSIG 166           // 64 x-signals + 2 w-signals + 100 templates
#define NTF 1024           // fwd block (radix-8 ladder, latency-bound regime)
#define NTI 512            // inv block (radix 2,16,16,16 ladder)
#define PI_F 3.14159265358979323846f
// cos/sin(2*pi/16): fwd stage-4 twiddle base (radix-8 ladder)
#define C8 0.92387953251128674f
#define S8 0.38268343236508978f
#define R2_F 0.70710678118654752f

typedef float cf2 __attribute__((ext_vector_type(2)));

// Lessons encoded in this structure:
//  R5: scattered per-lane twiddle table loads stall VMEM -> power chain from 1 load.
//  R6: XOR swizzle + cf2 packed math + algebraic per-stage indices = best layout.
//  R7: +1-per-32 pad layout TRIPLES bank conflicts vs XOR swizzle (FFT tiles).
//  R8: __shfl_xor compiles to ds_bpermute (LDS pipe!) - shfl stage fusion loses.
//  R9: inv is ISSUE-bound, not occupancy-bound (radix-8/1024t: occ 2x, dur +9%).
//  R10/R11: VOP3P pk asm for cmul + product pass: VALU 74->58%, inv 69->65us.
//  R12: head LDS-staged: neutral. Residual = fwd (~15-25us) + harness overhead.
//  R13 REVERTED: pair-based fwd untangle broke global write coalescing (+4.7us).
//  R14 REVERTED: DPP-fused final radix-2 cost +8.4us - DPP consumers need
//      s_nop wait-states after producer VALU ops; 32 dependent DPP chains
//      serialize. NO cross-lane fusion of the radix-2, period.
//  R15 (this round): radix-2 stage moved FIRST, fused into the product pass
//      IN-THREAD (no cross-lane): each thread composes the 4-group
//      {f, 4096-f, 4096+f, 8192-f} (same 16 products/thread) and applies two
//      radix-2 butterflies in registers. Remaining 16,16,16 stages on two
//      4096-halves; the stride-1 last stage has twiddle W16^0 = 1 -> s3 is
//      read-only b128 + dft16 + max: -44 pk (twiddle chain), -16 LDS writes,
//      -8 b128 reads, -1 barrier. T[4096-f] = -i*conj(T[f]); Wi^f = conj(T[2f]);
//      Wi^{4096-f} = -T[2f].

// Packed complex multiply: 2 VOP3P instructions.
__device__ __forceinline__ cf2 cmul(cf2 a, cf2 b) {
    cf2 t, d;
    asm("v_pk_mul_f32 %0, %1, %2 op_sel:[0,0] op_sel_hi:[0,1]"
        : "=v"(t) : "v"(a), "v"(b));
    asm("v_pk_fma_f32 %0, %1, %2, %3 op_sel:[1,1,0] op_sel_hi:[1,0,1] neg_lo:[0,1,0]"
        : "=v"(d) : "v"(a), "v"(b), "v"(t));
    return d;
}
// a * conj(b): re = ax*bx + ay*by, im = ay*bx - ax*by. 2 VOP3P insts.
__device__ __forceinline__ cf2 cmulc(cf2 a, cf2 b) {
    cf2 t, d;
    asm("v_pk_mul_f32 %0, %1, %2 op_sel:[0,0] op_sel_hi:[0,1] neg_hi:[0,1]"
        : "=v"(t) : "v"(a), "v"(b));   // {ax*bx, -ax*by}
    asm("v_pk_fma_f32 %0, %1, %2, %3 op_sel:[1,1,0] op_sel_hi:[1,0,1]"
        : "=v"(d) : "v"(a), "v"(b), "v"(t));
    return d;
}
// conj(a) * b: re = ax*bx + ay*by, im = ax*by - ay*bx. 2 VOP3P insts.
__device__ __forceinline__ cf2 cmulca(cf2 a, cf2 b) {
    cf2 t, d;
    asm("v_pk_mul_f32 %0, %1, %2 op_sel:[0,0] op_sel_hi:[0,1]"
        : "=v"(t) : "v"(a), "v"(b));   // {ax*bx, ax*by}
    asm("v_pk_fma_f32 %0, %1, %2, %3 op_sel:[1,1,0] op_sel_hi:[1,0,1] neg_hi:[1,0,0]"
        : "=v"(d) : "v"(a), "v"(b), "v"(t));
    return d;
}
// {ax+bx, ay-by}
__device__ __forceinline__ cf2 pk_addch(cf2 a, cf2 b) {
    cf2 d;
    asm("v_pk_add_f32 %0, %1, %2 neg_hi:[0,1]" : "=v"(d) : "v"(a), "v"(b));
    return d;
}
// {ax-bx, ay+by}
__device__ __forceinline__ cf2 pk_subcl(cf2 a, cf2 b) {
    cf2 d;
    asm("v_pk_add_f32 %0, %1, %2 neg_lo:[0,1]" : "=v"(d) : "v"(a), "v"(b));
    return d;
}
// {s.x - r.y, s.y + r.x}  (= s + i*r)
__device__ __forceinline__ cf2 pk_compose1(cf2 s, cf2 r) {
    cf2 d;
    asm("v_pk_add_f32 %0, %1, %2 op_sel:[0,1] op_sel_hi:[0,0] neg_lo:[0,1]"
        : "=v"(d) : "v"(s), "v"(r));
    return d;
}
// {s.x + r.y, r.x - s.y}  (= conj(s - i*r))
__device__ __forceinline__ cf2 pk_compose2(cf2 s, cf2 r) {
    cf2 d;
    asm("v_pk_add_f32 %0, %1, %2 op_sel:[0,1] op_sel_hi:[0,0] neg_hi:[1,0]"
        : "=v"(d) : "v"(s), "v"(r));
    return d;
}
template<int SIGN>
__device__ __forceinline__ cf2 rot90(cf2 z) {
    return (SIGN < 0) ? (cf2){z.y, -z.x} : (cf2){-z.y, z.x};
}
template<int SIGN>
__device__ __forceinline__ cf2 ldT(const cf2* __restrict__ T, int idx) {
    cf2 t = T[idx];
    if (SIGN > 0) t.y = -t.y;
    return t;
}

// LDS bank swizzle. Even XOR keeps float4 pair adjacency; involution.
__device__ __forceinline__ int swz(int i) { return i ^ (((i >> 5) & 15) << 1); }

// Digit reversal for fwd's radix 8,8,8,8,2 DIF ladder.
__device__ __forceinline__ int pos8(int f) {
    return ((f & 7) << 10) | (((f >> 3) & 7) << 7) |
           (((f >> 6) & 7) << 4) | (((f >> 9) & 7) << 1) | ((f >> 12) & 1);
}

// ---------------- radix-16 pieces (inv kernel) ----------------
template<int SIGN>
__device__ __forceinline__ void dft16(cf2 x[16]) {
    const float S = (SIGN < 0) ? -1.f : 1.f;
    const cf2 w1 = {0.9238795325112867f, S * 0.3826834323650898f};
    const cf2 w2 = {0.7071067811865476f, S * 0.7071067811865476f};
    const cf2 w3 = {0.3826834323650898f, S * 0.9238795325112867f};
    cf2 v[16];
    #pragma unroll
    for (int n1 = 0; n1 < 4; ++n1) {
        cf2 a0 = x[n1], a1 = x[n1+4], a2 = x[n1+8], a3 = x[n1+12];
        cf2 t0 = a0 + a2, t2 = a0 - a2;
        cf2 t1 = a1 + a3, t3 = rot90<SIGN>(a1 - a3);
        cf2 u0 = t0 + t1, u1 = t2 + t3;
        cf2 u2 = t0 - t1, u3 = t2 - t3;
        if (n1 == 1) { u1 = cmul(u1, w1); u2 = cmul(u2, w2); u3 = cmul(u3, w3); }
        else if (n1 == 2) { u1 = cmul(u1, w2); u2 = rot90<SIGN>(u2);
                            u3 = rot90<SIGN>(cmul(u3, w2)); }
        else if (n1 == 3) { u1 = cmul(u1, w3); u2 = rot90<SIGN>(cmul(u2, w2));
                            u3 = -cmul(u3, w1); }
        v[0*4+n1] = u0; v[1*4+n1] = u1; v[2*4+n1] = u2; v[3*4+n1] = u3;
    }
    #pragma unroll
    for (int r = 0; r < 4; ++r) {
        cf2 a0 = v[r*4+0], a1 = v[r*4+1], a2 = v[r*4+2], a3 = v[r*4+3];
        cf2 t0 = a0 + a2, t2 = a0 - a2;
        cf2 t1 = a1 + a3, t3 = rot90<SIGN>(a1 - a3);
        x[r]    = t0 + t1; x[r+4]  = t2 + t3;
        x[r+8]  = t0 - t1; x[r+12] = t2 - t3;
    }
}

template<int SIGN>
__device__ __forceinline__ void butterfly16(cf2* A, const int idx[16], cf2 w1) {
    cf2 x[16];
    #pragma unroll
    for (int n = 0; n < 16; ++n) x[n] = A[idx[n]];
    dft16<SIGN>(x);
    A[idx[0]] = x[0];
    A[idx[1]] = cmul(x[1], w1);
    const cf2 w2 = cmul(w1, w1);
    A[idx[2]] = cmul(x[2], w2);
    const cf2 w3 = cmul(w1, w2);
    A[idx[3]] = cmul(x[3], w3);
    const cf2 w4 = cmul(w2, w2);
    A[idx[4]] = cmul(x[4], w4);
    A[idx[5]] = cmul(x[5], cmul(w1, w4));
    A[idx[6]] = cmul(x[6], cmul(w2, w4));
    A[idx[7]] = cmul(x[7], cmul(w3, w4));
    const cf2 w8 = cmul(w4, w4);
    A[idx[8]]  = cmul(x[8],  w8);
    A[idx[9]]  = cmul(x[9],  cmul(w1, w8));
    A[idx[10]] = cmul(x[10], cmul(w2, w8));
    A[idx[11]] = cmul(x[11], cmul(w3, w8));
    const cf2 w12 = cmul(w4, w8);
    A[idx[12]] = cmul(x[12], w12);
    A[idx[13]] = cmul(x[13], cmul(w1, w12));
    A[idx[14]] = cmul(x[14], cmul(w2, w12));
    A[idx[15]] = cmul(x[15], cmul(w3, w12));
}

// ---------------- radix-8 pieces (fwd kernel) ----------------
template<int SIGN>
__device__ __forceinline__ void dft8(cf2 x[8]) {
    const cf2 w81 = { R2_F, SIGN * R2_F };
    const cf2 w83 = { -R2_F, SIGN * R2_F };
    cf2 u0 = x[0] + x[4], u1 = x[1] + x[5], u2 = x[2] + x[6], u3 = x[3] + x[7];
    cf2 v0 = x[0] - x[4];
    cf2 v1 = cmul(x[1] - x[5], w81);
    cf2 v2 = rot90<SIGN>(x[2] - x[6]);
    cf2 v3 = cmul(x[3] - x[7], w83);
    cf2 t0 = u0 + u2, t2 = u0 - u2;
    cf2 t1 = u1 + u3, t3 = rot90<SIGN>(u1 - u3);
    x[0] = t0 + t1; x[2] = t2 + t3; x[4] = t0 - t1; x[6] = t2 - t3;
    cf2 s0 = v0 + v2, s2 = v0 - v2;
    cf2 s1 = v1 + v3, s3 = rot90<SIGN>(v1 - v3);
    x[1] = s0 + s1; x[3] = s2 + s3; x[5] = s0 - s1; x[7] = s2 - s3;
}

template<int SIGN>
__device__ __forceinline__ void butterfly8(cf2* A, const int idx[8], cf2 w1) {
    cf2 x[8];
    #pragma unroll
    for (int n = 0; n < 8; ++n) x[n] = A[idx[n]];
    dft8<SIGN>(x);
    A[idx[0]] = x[0];
    A[idx[1]] = cmul(x[1], w1);
    const cf2 w2 = cmul(w1, w1);
    A[idx[2]] = cmul(x[2], w2);
    const cf2 w3 = cmul(w1, w2);
    A[idx[3]] = cmul(x[3], w3);
    const cf2 w4 = cmul(w2, w2);
    A[idx[4]] = cmul(x[4], w4);
    A[idx[5]] = cmul(x[5], cmul(w1, w4));
    A[idx[6]] = cmul(x[6], cmul(w2, w4));
    A[idx[7]] = cmul(x[7], cmul(w3, w4));
}

// ---------------------------------------------------------------------------
// Kernel 1: forward real FFT (length 16384) via 8192-pt complex FFT.
// Radix 8,8,8,8,2 ladder, 1024 threads. Blocks [NSIG, NSIG+16) build the
// twiddle table T via quadrant-reduced float sincos. W blocks (sig 64/65)
// write V(f) = conj(W(f)) * e^{-i pi k/8192}, k = 4094*f mod 16384.
// ---------------------------------------------------------------------------
__global__ __launch_bounds__(NTF, 4)
void fwd_fft_kernel(const float* __restrict__ xi, const float* __restrict__ w,
                    const float* __restrict__ tmpl, cf2* __restrict__ Tw,
                    cf2* __restrict__ spec) {
    __shared__ __attribute__((aligned(16))) cf2 A[M_LEN];   // 64 KB
    const int sig = blockIdx.x;
    const int tid = threadIdx.x;

    if (sig >= NSIG) {   // twiddle writer: T[k] = e^{-2 pi i k / 16384}
        const int k = (sig - NSIG) * NTF + tid;
        const int quad = k >> 12, mm = k & 4095;
        float s, c; __sincosf(PI_F * (float)mm / 8192.f, &s, &c);
        cf2 v;   // (cos th, -sin th), th = pi k/8192 = quad*pi/2 + t
        if      (quad == 0) v = (cf2){ c, -s};
        else if (quad == 1) v = (cf2){-s, -c};
        else if (quad == 2) v = (cf2){-c,  s};
        else                v = (cf2){ s,  c};
        Tw[k] = v;
        return;
    }

    const float* src;
    int nre;
    if (sig < 64)      { src = xi   + sig * L_LEN;         nre = L_LEN; }
    else if (sig < 66) { src = w    + (sig - 64) * L_LEN;  nre = L_LEN; }
    else               { src = tmpl + (sig - 66) * KT_LEN; nre = KT_LEN; }
    const bool isW = (sig >= 64 && sig < 66);
    const int nc = nre >> 1;
    const float4* s4 = (const float4*)src;
    const int g0 = tid ^ ((tid >> 4) & 15);
    #pragma unroll
    for (int m = 0; m < 4; ++m) {
        const int u = 2*tid + 2048*m;
        float4 vv = (u < nc) ? s4[tid + 1024*m] : make_float4(0.f, 0.f, 0.f, 0.f);
        ((float4*)A)[g0 + 1024*m] = vv;
    }
    __syncthreads();

    {   // stage 1: stride 1024, w1 = W_8192^tid
        int idx[8]; const int b0 = swz(tid);
        #pragma unroll
        for (int n = 0; n < 8; ++n) idx[n] = b0 + 1024*n;
        float sn, cs; __sincosf(-PI_F * (float)(2*tid) / 8192.f, &sn, &cs);
        butterfly8<-1>(A, idx, (cf2){cs, sn});
    }
    __syncthreads();
    {   // stage 2: stride 128, w1 = W_1024^j
        const int blk = tid >> 7, j = tid & 127, jb = blk*1024;
        const int jsw = j ^ (((j >> 5) & 3) << 1);
        int idx[8];
        #pragma unroll
        for (int n = 0; n < 8; ++n) idx[n] = jb + 128*n + (jsw ^ ((n & 3) << 3));
        float sn, cs; __sincosf(-PI_F * (float)(16*j) / 8192.f, &sn, &cs);
        butterfly8<-1>(A, idx, (cf2){cs, sn});
    }
    __syncthreads();
    {   // stage 3: stride 16, w1 = W_128^j
        const int blk = tid >> 4, j = tid & 15;
        const int base = blk*128 + j, bx = (blk & 3) << 3;
        int idx[8];
        #pragma unroll
        for (int n = 0; n < 8; ++n) idx[n] = (base + 16*n) ^ bx ^ ((n >> 1) << 1);
        float sn, cs; __sincosf(-PI_F * (float)(128*j) / 8192.f, &sn, &cs);
        butterfly8<-1>(A, idx, (cf2){cs, sn});
    }
    __syncthreads();
    {   // stage 4: stride 2, w1 = W_16^j (constant)
        const int blk = tid >> 1, j = tid & 1;
        const int Xa = ((blk >> 1) & 15) << 1;
        const int base = ((blk << 4) | j) ^ (Xa & 16);
        const int xv = Xa & 14;
        int idx[8];
        #pragma unroll
        for (int n = 0; n < 8; ++n) idx[n] = base + ((2*n) ^ xv);
        cf2 w1 = j ? (cf2){C8, -S8} : (cf2){1.f, 0.f};
        butterfly8<-1>(A, idx, w1);
    }
    __syncthreads();
    // Final radix-2 (stride 1, no twiddle), b128 in-place.
    #pragma unroll
    for (int m = 0; m < 4; ++m) {
        float4 pq = ((float4*)A)[g0 + 1024*m];
        ((float4*)A)[g0 + 1024*m] = make_float4(pq.x + pq.z, pq.y + pq.w,
                                                pq.x - pq.z, pq.y - pq.w);
    }
    __syncthreads();

    // Untangle packed result to real-signal spectrum X[f], f = 0..M.
    cf2* out = spec + (size_t)sig * SPEC_STRIDE;
    #pragma unroll
    for (int m = 0; m < 8; ++m) {
        const int f = tid + 1024*m;
        const int fb = (M_LEN - f) & (M_LEN - 1);
        cf2 Za = A[swz(pos8(f))];
        cf2 Zb = A[swz(pos8(fb))];
        cf2 E = (cf2){0.5f*(Za.x + Zb.x), 0.5f*(Za.y - Zb.y)};
        cf2 D = (cf2){Za.x - Zb.x, Za.y + Zb.y};
        cf2 O = (cf2){0.5f*D.y, -0.5f*D.x};
        float sn, cs;
        __sincosf(-PI_F * (float)f / 8192.f, &sn, &cs);
        cf2 val = E + (cf2){cs*O.x - sn*O.y, cs*O.y + sn*O.x};
        if (isW) {   // V(f) = conj(W(f)) * e^{-i pi k/8192}, k exact int mod
            const int k = (4094 * f) & (L_LEN - 1);
            float psn, pcs; __sincosf(-PI_F * (float)k / 8192.f, &psn, &pcs);
            val = cmul((cf2){val.x, -val.y}, (cf2){pcs, psn});
        }
        out[f] = val;
    }
    if (tid == 0) {   // f = 8192
        cf2 Za = A[swz(0)];
        cf2 val = (cf2){Za.x - Za.y, 0.f};
        if (isW) {   // k(8192) = 8192 -> phase = (-1, 0)
            val = (cf2){-val.x, 0.f};
        }
        out[M_LEN] = val;
    }
}

// ---------------------------------------------------------------------------
// Kernel 2 (R15): product + Hermitian pack + FIRST radix-2 stage fused in
// registers (in-thread; no cross-lane). Then 16,16,16 stages on the two
// 4096-halves; the stride-1 last stage (twiddle = 1) is read-only + max.
// Z' carries 2x (0.5 dropped) -> divide by 2*M*hh.
// ---------------------------------------------------------------------------
__global__ __launch_bounds__(NTI, 4)
void inv_fft_kernel(const cf2* __restrict__ spec, const cf2* __restrict__ T,
                    const float* __restrict__ hh, float* __restrict__ zarr) {
    __shared__ __attribute__((aligned(16))) cf2 A[M_LEN];   // 64 KB
    const int idx0 = blockIdx.x;
    const int c = idx0 & 1;
    const int n = (idx0 >> 1) % NTPL;
    const int b = idx0 / (2 * NTPL);
    const int tid = threadIdx.x;

    const cf2* Xs = spec + (size_t)(b*2 + c)      * SPEC_STRIDE;
    const cf2* Vs = spec + (size_t)(64 + c)       * SPEC_STRIDE;
    const cf2* Hs = spec + (size_t)(66 + n*2 + c) * SPEC_STRIDE;
    const float4* X4 = (const float4*)Xs;
    const float4* V4 = (const float4*)Vs;
    const float4* H4 = (const float4*)Hs;
    const float4* T4 = (const float4*)T;

    // Phase 1: per t' = tid + 512m, pair f0 = 2t', f1 = 2t'+1.
    // 4-group per f: products at f, 4096-f, 4096+f, 8192-f ->
    // Z'[f], Z'[8192-f] (compose at u=f, twiddle T[f]) and
    // Z'[4096-f], Z'[4096+f] (compose at u=4096-f, twiddle -i*conj(T[f])).
    // Radix-2: (Z'[f], Z'[4096+f]) with conj(T[2f]); (Z'[4096-f], Z'[8192-f])
    // with -T[2f].  ytop -> A[0,4096), ybot -> A[4096,8192), swizzled.
    #pragma unroll
    for (int m = 0; m < 2; ++m) {
        const int tp = tid + 512*m;
        const int f0 = 2*tp, f1 = f0 + 1;
        float4 xa = X4[tp],        va = V4[tp],        ha = H4[tp];
        float4 xq = X4[tp + 2048], vq = V4[tp + 2048], hq = H4[tp + 2048];
        cf2 PA0 = cmulc(cmul((cf2){xa.x, xa.y}, (cf2){va.x, va.y}), (cf2){ha.x, ha.y});
        cf2 PA1 = cmulc(cmul((cf2){xa.z, xa.w}, (cf2){va.z, va.w}), (cf2){ha.z, ha.w});
        cf2 QB0 = cmulc(cmul((cf2){xq.x, xq.y}, (cf2){vq.x, vq.y}), (cf2){hq.x, hq.y});
        cf2 QB1 = cmulc(cmul((cf2){xq.z, xq.w}, (cf2){vq.z, vq.w}), (cf2){hq.z, hq.w});
        cf2 PB0 = cmulc(cmul(Xs[4096 - f0], Vs[4096 - f0]), Hs[4096 - f0]);
        cf2 PB1 = cmulc(cmul(Xs[4096 - f1], Vs[4096 - f1]), Hs[4096 - f1]);
        cf2 QA0 = cmulc(cmul(Xs[8192 - f0], Vs[8192 - f0]), Hs[8192 - f0]);
        cf2 QA1 = cmulc(cmul(Xs[8192 - f1], Vs[8192 - f1]), Hs[8192 - f1]);
        float4 tf4 = T4[tp];            // T[f0], T[f1]
        float4 t2a = T4[2*tp];          // T[2f0] in .xy
        float4 t2b = T4[2*tp + 1];      // T[2f1] in .xy
        cf2 Tf0 = (cf2){tf4.x, tf4.y}, Tf1 = (cf2){tf4.z, tf4.w};
        cf2 T20 = (cf2){t2a.x, t2a.y}, T21 = (cf2){t2b.x, t2b.y};
        // --- f0 ---
        cf2 SpA0 = pk_addch(PA0, QA0), SmA0 = pk_subcl(PA0, QA0);
        cf2 RA0 = cmulca(Tf0, SmA0);
        cf2 ZA1_0 = pk_compose1(SpA0, RA0);     // Z'[f0]
        cf2 ZA2_0 = pk_compose2(SpA0, RA0);     // Z'[8192-f0]
        cf2 tB0 = (cf2){-Tf0.y, -Tf0.x};        // T[4096-f0]
        cf2 SpB0 = pk_addch(PB0, QB0), SmB0 = pk_subcl(PB0, QB0);
        cf2 RB0 = cmulca(tB0, SmB0);
        cf2 ZB1_0 = pk_compose1(SpB0, RB0);     // Z'[4096-f0]
        cf2 ZB2_0 = pk_compose2(SpB0, RB0);     // Z'[4096+f0]
        cf2 top0 = ZA1_0 + ZB2_0;
        cf2 bot0 = cmulca(T20, ZA1_0 - ZB2_0);
        // --- f1 ---
        cf2 SpA1 = pk_addch(PA1, QA1), SmA1 = pk_subcl(PA1, QA1);
        cf2 RA1 = cmulca(Tf1, SmA1);
        cf2 ZA1_1 = pk_compose1(SpA1, RA1);
        cf2 ZA2_1 = pk_compose2(SpA1, RA1);
        cf2 tB1 = (cf2){-Tf1.y, -Tf1.x};
        cf2 SpB1 = pk_addch(PB1, QB1), SmB1 = pk_subcl(PB1, QB1);
        cf2 RB1 = cmulca(tB1, SmB1);
        cf2 ZB1_1 = pk_compose1(SpB1, RB1);
        cf2 ZB2_1 = pk_compose2(SpB1, RB1);
        cf2 top1 = ZA1_1 + ZB2_1;
        cf2 bot1 = cmulca(T21, ZA1_1 - ZB2_1);
        // coalesced swizzled float4 writes for the fwd side
        const int gt = tp ^ ((tp >> 4) & 15);
        ((float4*)A)[gt]        = make_float4(top0.x, top0.y, top1.x, top1.y);
        ((float4*)A)[2048 + gt] = make_float4(bot0.x, bot0.y, bot1.x, bot1.y);
        // rev-side butterflies (skip f0 == 0: its pair (4096,8192) is invalid;
        // the fwd butterfly above already used the correct self-paired Z'[4096])
        if (tp > 0) {
            cf2 tr0 = ZB1_0 + ZA2_0;
            cf2 dr0 = cmul(ZB1_0 - ZA2_0, T20);
            A[swz(4096 - f0)] = tr0;
            A[swz(8192 - f0)] = -dr0;
        }
        cf2 tr1 = ZB1_1 + ZA2_1;
        cf2 dr1 = cmul(ZB1_1 - ZA2_1, T21);
        A[swz(4096 - f1)] = tr1;
        A[swz(8192 - f1)] = -dr1;
    }
    if (tid == 0) {   // f = 2048 butterfly (2048, 6144), Wi^2048 = +i
        cf2 P = cmulc(cmul(Xs[2048], Vs[2048]), Hs[2048]);
        cf2 Q = cmulc(cmul(Xs[6144], Vs[6144]), Hs[6144]);
        cf2 Tc = (cf2){R2_F, -R2_F};           // T[2048]
        cf2 Sp = pk_addch(P, Q), Sm = pk_subcl(P, Q);
        cf2 R = cmulca(Tc, Sm);
        cf2 Z1 = pk_compose1(Sp, R), Z2 = pk_compose2(Sp, R);
        cf2 d = Z1 - Z2;
        A[swz(2048)] = Z1 + Z2;
        A[swz(6144)] = (cf2){-d.y, d.x};
    }
    __syncthreads();

    {   // stage 1 of the 4096-halves: stride 256, w1 = conj(T[4j])
        const int h = tid >> 8, j = tid & 255;
        const int Hb = h << 12;
        const int jx = j ^ (((j >> 5) & 7) << 1);
        int idx[16];
        #pragma unroll
        for (int nn = 0; nn < 16; ++nn)
            idx[nn] = Hb + 256*nn + (jx ^ ((nn & 1) << 4));
        butterfly16<+1>(A, idx, ldT<+1>(T, 4*j));
    }
    __syncthreads();
    {   // stage 2: stride 16, w1 = conj(T[64j])
        const int h = tid >> 8, q = (tid >> 4) & 15, j = tid & 15;
        const int base = (h << 12) + (q << 8);
        const int qb = q & 1;
        int idx[16];
        #pragma unroll
        for (int nn = 0; nn < 16; ++nn)
            idx[nn] = base + 16*(nn ^ qb) + (j ^ (((nn >> 1) & 7) << 1));
        butterfly16<+1>(A, idx, ldT<+1>(T, 64*j));
    }
    __syncthreads();

    // stage 3: stride 1, twiddle = W_16^0 = 1 -> read-only dft16 + max.
    float mx = -INFINITY;
    {
        const int bb = 16 * (tid ^ ((tid >> 4) & 1));
        const int m3 = ((tid >> 1) & 7) << 1;
        cf2 x[16];
        #pragma unroll
        for (int e = 0; e < 8; ++e) {
            float4 v = ((const float4*)A)[(bb + ((2*e) ^ m3)) >> 1];
            x[2*e]     = (cf2){v.x, v.y};
            x[2*e + 1] = (cf2){v.z, v.w};
        }
        dft16<+1>(x);
        #pragma unroll
        for (int nn = 0; nn < 16; ++nn)
            mx = fmaxf(mx, fmaxf(x[nn].x, x[nn].y));
    }
    __syncthreads();   // all stage-3 reads done before reusing A as scratch
    for (int off = 32; off > 0; off >>= 1)
        mx = fmaxf(mx, __shfl_xor(mx, off));
    const int lane = tid & 63, wv = tid >> 6;   // 8 waves
    float* redf = (float*)A;
    if (lane == 0) redf[wv] = mx;
    __syncthreads();
    if (tid == 0) {
        float mm = redf[0];
        for (int i = 1; i < NTI/64; ++i) mm = fmaxf(mm, redf[i]);
        zarr[(b*2 + c)*NTPL + n] = mm / (2.f * (float)M_LEN * hh[n*2 + c]);
    }
}

// ---------------------------------------------------------------------------
// Kernel 3: tiny CNN/MLP head. One block per batch element.
// R12: all weights staged in LDS (coalesced), all MAC loops unrolled over
// LDS reads, fc1 parallelized 32 outputs x 8 lanes + shfl_xor tree.
// ---------------------------------------------------------------------------
#define W1_OFF 0        // 16x6 = 96
#define B1_OFF 96       // 16
#define W2_OFF 112      // 32x48 = 1536
#define B2_OFF 1648     // 32
#define W3_OFF 1680     // 32x132 (padded from 128) = 4224
#define B3_OFF 5904     // 32
#define W4_OFF 5936     // 2x32 = 64
#define B4_OFF 6000     // 2
#define WSM_SZ 6002

__global__ __launch_bounds__(256)
void head_kernel(const float* __restrict__ zarr,
                 const float* __restrict__ W1, const float* __restrict__ b1,
                 const float* __restrict__ W2, const float* __restrict__ b2,
                 const float* __restrict__ W3, const float* __restrict__ b3,
                 const float* __restrict__ W4, const float* __restrict__ b4,
                 float* __restrict__ out) {
    __shared__ float wsm[WSM_SZ];
    __shared__ float zl[2*NTPL];
    __shared__ float s1[16*48];
    __shared__ float p1[16*16];
    __shared__ float s2[32*14];
    __shared__ float hflat[128];
    __shared__ float h1[32];
    const int b = blockIdx.x, tid = threadIdx.x;

    for (int i = tid; i < 96;   i += 256) wsm[W1_OFF + i] = W1[i];
    if (tid < 16)                         wsm[B1_OFF + tid] = b1[tid];
    for (int i = tid; i < 1536; i += 256) wsm[W2_OFF + i] = W2[i];
    if (tid < 32)                         wsm[B2_OFF + tid] = b2[tid];
    for (int i = tid; i < 4096; i += 256)
        wsm[W3_OFF + (i >> 7)*132 + (i & 127)] = W3[i];
    if (tid < 32)                         wsm[B3_OFF + tid] = b3[tid];
    if (tid < 64)                         wsm[W4_OFF + tid] = W4[tid];
    if (tid < 2)                          wsm[B4_OFF + tid] = b4[tid];
    for (int i = tid; i < 2*NTPL; i += 256) zl[i] = zarr[b*2*NTPL + i];
    __syncthreads();

    for (int i = tid; i < 16*48; i += 256) {
        const int o = i / 48, t = i % 48;
        float acc = wsm[B1_OFF + o];
        #pragma unroll
        for (int cc = 0; cc < 2; ++cc)
            #pragma unroll
            for (int k = 0; k < 3; ++k)
                acc += zl[cc*NTPL + t + k] * wsm[W1_OFF + o*6 + cc*3 + k];
        s1[i] = 1.f / (1.f + __expf(-acc));
    }
    __syncthreads();
    for (int i = tid; i < 16*16; i += 256) {
        const int o = i / 16, u = i % 16;
        p1[i] = fmaxf(fmaxf(s1[o*48 + 3*u], s1[o*48 + 3*u+1]), s1[o*48 + 3*u+2]);
    }
    __syncthreads();
    for (int i = tid; i < 32*14; i += 256) {
        const int o = i / 14, t = i % 14;
        float acc = wsm[B2_OFF + o];
        #pragma unroll
        for (int cc = 0; cc < 16; ++cc)
            #pragma unroll
            for (int k = 0; k < 3; ++k)
                acc += p1[cc*16 + t + k] * wsm[W2_OFF + o*48 + cc*3 + k];
        s2[o*14 + t] = 1.f / (1.f + __expf(-acc));
    }
    __syncthreads();
    for (int i = tid; i < 128; i += 256) {
        const int o = i / 4, u = i % 4;
        hflat[i] = fmaxf(fmaxf(s2[o*14 + 3*u], s2[o*14 + 3*u+1]), s2[o*14 + 3*u+2]);
    }
    __syncthreads();
    {
        const int o = tid >> 3, lg = tid & 7;
        float acc = 0.f;
        #pragma unroll
        for (int k = 0; k < 16; ++k)
            acc += hflat[lg + 8*k] * wsm[W3_OFF + o*132 + lg + 8*k];
        acc += __shfl_xor(acc, 1);
        acc += __shfl_xor(acc, 2);
        acc += __shfl_xor(acc, 4);
        if (lg == 0) h1[o] = fmaxf(acc + wsm[B3_OFF + o], 0.f);
    }
    __syncthreads();
    if (tid < 64) {
        const int o = tid >> 5, j = tid & 31;
        float p = h1[j] * wsm[W4_OFF + o*32 + j];
        p += __shfl_xor(p, 1);
        p += __shfl_xor(p, 2);
        p += __shfl_xor(p, 4);
        p += __shfl_xor(p, 8);
        p += __shfl_xor(p, 16);
        if (j == 0) out[b*2 + o] = p + wsm[B4_OFF + o];
    }
}

extern "C" void kernel_launch(void* const* d_in, const int* in_sizes, int n_in,
                              void* d_out, int out_size, void* d_ws, size_t ws_size,
                              hipStream_t stream) {
    const float* xi   = (const float*)d_in[0];
    const float* Sw   = (const float*)d_in[1];
    const float* tmpl = (const float*)d_in[2];
    const float* hh   = (const float*)d_in[3];
    const float* W1   = (const float*)d_in[4];
    const float* b1   = (const float*)d_in[5];
    const float* W2   = (const float*)d_in[6];
    const float* b2   = (const float*)d_in[7];
    const float* W3   = (const float*)d_in[8];
    const float* b3   = (const float*)d_in[9];
    const float* W4   = (const float*)d_in[10];
    const float* b4   = (const float*)d_in[11];
    float* out = (float*)d_out;

    cf2* T16  = (cf2*)d_ws;                         // 16384 cf2 = 128 KB
    cf2* spec = T16 + 16384;                        // NSIG * SPEC_STRIDE cf2
    float* zarr = (float*)(spec + (size_t)NSIG * SPEC_STRIDE);

    fwd_fft_kernel<<<dim3(NSIG + 16), dim3(NTF), 0, stream>>>(xi, Sw, tmpl, T16, spec);
    inv_fft_kernel<<<dim3(BB * NTPL * 2), dim3(NTI), 0, stream>>>(spec, T16, hh, zarr);
    head_kernel<<<dim3(BB), dim3(256), 0, stream>>>(zarr, W1, b1, W2, b2, W3, b3, W4, b4, out);
}

// Round 8
// 152.012 us; speedup vs baseline: 1.0379x; 1.0166x over previous
//
#include <hip/hip_runtime.h>
#include <math.h>

#define L_LEN 16384
#define M_LEN 8192
#define KT_LEN 4096
#define BB 32
#define NTPL 50
#define SPEC_STRIDE 8224   // complex slots per signal (>= 8193)
#define NSIG 166           // 64 x-signals + 2 w-signals + 100 templates
#define NTF 1024           // fwd block (radix-8 ladder, latency-bound regime)
#define NTI 512            // inv block (radix 2,16,16,16 ladder)
#define PI_F 3.14159265358979323846f
// cos/sin(2*pi/16): fwd stage-4 twiddle base (radix-8 ladder)
#define C8 0.92387953251128674f
#define S8 0.38268343236508978f
#define R2_F 0.70710678118654752f

typedef float cf2 __attribute__((ext_vector_type(2)));

// Lessons encoded in this structure:
//  R5: scattered per-lane twiddle table loads stall VMEM -> power chain from 1 load.
//  R6: XOR swizzle + cf2 packed math + algebraic per-stage indices = best layout.
//  R7: +1-per-32 pad layout TRIPLES bank conflicts vs XOR swizzle (FFT tiles).
//  R8: __shfl_xor compiles to ds_bpermute (LDS pipe!) - shfl stage fusion loses.
//  R9: inv is not occupancy-bound (radix-8/1024t: occ 2x, dur +9%).
//  R10/R11: VOP3P pk asm for cmul + product pass: VALU 74->58%, inv 69->65us.
//  R12: head LDS-staged: neutral. Residual = fwd (~15-25us) + harness overhead.
//  R13 REVERTED: pair-based fwd untangle broke global write coalescing (+4.7us).
//  R14 REVERTED: DPP-fused radix-2 cost +8.4us (s_nop wait-states serialize).
//  R15: radix-2-first + read-only last stage: VALU 58.6->53.5% but dur FLAT
//      (66us) -> stages/VALU are OFF the critical path. Remaining floor:
//      product-phase L2 traffic (3 spectra x 3200 blocks = 736 MB = ~21us at
//      34.5 TB/s aggregate L2) + partial overlap at 2 blocks/CU.
//  R16 (this round): hoist X*V out of inv - it was recomputed 50x (once per
//      template). xv_kernel (64 blocks, IN-PLACE into X's spec slots, no new
//      workspace) between fwd and inv. inv product: cmulc(XV,H) - loads
//      36->24/thread, L2 traffic -28%, VALU -32 insts/thread.

// Packed complex multiply: 2 VOP3P instructions.
__device__ __forceinline__ cf2 cmul(cf2 a, cf2 b) {
    cf2 t, d;
    asm("v_pk_mul_f32 %0, %1, %2 op_sel:[0,0] op_sel_hi:[0,1]"
        : "=v"(t) : "v"(a), "v"(b));
    asm("v_pk_fma_f32 %0, %1, %2, %3 op_sel:[1,1,0] op_sel_hi:[1,0,1] neg_lo:[0,1,0]"
        : "=v"(d) : "v"(a), "v"(b), "v"(t));
    return d;
}
// a * conj(b): re = ax*bx + ay*by, im = ay*bx - ax*by. 2 VOP3P insts.
__device__ __forceinline__ cf2 cmulc(cf2 a, cf2 b) {
    cf2 t, d;
    asm("v_pk_mul_f32 %0, %1, %2 op_sel:[0,0] op_sel_hi:[0,1] neg_hi:[0,1]"
        : "=v"(t) : "v"(a), "v"(b));   // {ax*bx, -ax*by}
    asm("v_pk_fma_f32 %0, %1, %2, %3 op_sel:[1,1,0] op_sel_hi:[1,0,1]"
        : "=v"(d) : "v"(a), "v"(b), "v"(t));
    return d;
}
// conj(a) * b: re = ax*bx + ay*by, im = ax*by - ay*bx. 2 VOP3P insts.
__device__ __forceinline__ cf2 cmulca(cf2 a, cf2 b) {
    cf2 t, d;
    asm("v_pk_mul_f32 %0, %1, %2 op_sel:[0,0] op_sel_hi:[0,1]"
        : "=v"(t) : "v"(a), "v"(b));   // {ax*bx, ax*by}
    asm("v_pk_fma_f32 %0, %1, %2, %3 op_sel:[1,1,0] op_sel_hi:[1,0,1] neg_hi:[1,0,0]"
        : "=v"(d) : "v"(a), "v"(b), "v"(t));
    return d;
}
// {ax+bx, ay-by}
__device__ __forceinline__ cf2 pk_addch(cf2 a, cf2 b) {
    cf2 d;
    asm("v_pk_add_f32 %0, %1, %2 neg_hi:[0,1]" : "=v"(d) : "v"(a), "v"(b));
    return d;
}
// {ax-bx, ay+by}
__device__ __forceinline__ cf2 pk_subcl(cf2 a, cf2 b) {
    cf2 d;
    asm("v_pk_add_f32 %0, %1, %2 neg_lo:[0,1]" : "=v"(d) : "v"(a), "v"(b));
    return d;
}
// {s.x - r.y, s.y + r.x}  (= s + i*r)
__device__ __forceinline__ cf2 pk_compose1(cf2 s, cf2 r) {
    cf2 d;
    asm("v_pk_add_f32 %0, %1, %2 op_sel:[0,1] op_sel_hi:[0,0] neg_lo:[0,1]"
        : "=v"(d) : "v"(s), "v"(r));
    return d;
}
// {s.x + r.y, r.x - s.y}  (= conj(s - i*r))
__device__ __forceinline__ cf2 pk_compose2(cf2 s, cf2 r) {
    cf2 d;
    asm("v_pk_add_f32 %0, %1, %2 op_sel:[0,1] op_sel_hi:[0,0] neg_hi:[1,0]"
        : "=v"(d) : "v"(s), "v"(r));
    return d;
}
template<int SIGN>
__device__ __forceinline__ cf2 rot90(cf2 z) {
    return (SIGN < 0) ? (cf2){z.y, -z.x} : (cf2){-z.y, z.x};
}
template<int SIGN>
__device__ __forceinline__ cf2 ldT(const cf2* __restrict__ T, int idx) {
    cf2 t = T[idx];
    if (SIGN > 0) t.y = -t.y;
    return t;
}

// LDS bank swizzle. Even XOR keeps float4 pair adjacency; involution.
__device__ __forceinline__ int swz(int i) { return i ^ (((i >> 5) & 15) << 1); }

// Digit reversal for fwd's radix 8,8,8,8,2 DIF ladder.
__device__ __forceinline__ int pos8(int f) {
    return ((f & 7) << 10) | (((f >> 3) & 7) << 7) |
           (((f >> 6) & 7) << 4) | (((f >> 9) & 7) << 1) | ((f >> 12) & 1);
}

// ---------------- radix-16 pieces (inv kernel) ----------------
template<int SIGN>
__device__ __forceinline__ void dft16(cf2 x[16]) {
    const float S = (SIGN < 0) ? -1.f : 1.f;
    const cf2 w1 = {0.9238795325112867f, S * 0.3826834323650898f};
    const cf2 w2 = {0.7071067811865476f, S * 0.7071067811865476f};
    const cf2 w3 = {0.3826834323650898f, S * 0.9238795325112867f};
    cf2 v[16];
    #pragma unroll
    for (int n1 = 0; n1 < 4; ++n1) {
        cf2 a0 = x[n1], a1 = x[n1+4], a2 = x[n1+8], a3 = x[n1+12];
        cf2 t0 = a0 + a2, t2 = a0 - a2;
        cf2 t1 = a1 + a3, t3 = rot90<SIGN>(a1 - a3);
        cf2 u0 = t0 + t1, u1 = t2 + t3;
        cf2 u2 = t0 - t1, u3 = t2 - t3;
        if (n1 == 1) { u1 = cmul(u1, w1); u2 = cmul(u2, w2); u3 = cmul(u3, w3); }
        else if (n1 == 2) { u1 = cmul(u1, w2); u2 = rot90<SIGN>(u2);
                            u3 = rot90<SIGN>(cmul(u3, w2)); }
        else if (n1 == 3) { u1 = cmul(u1, w3); u2 = rot90<SIGN>(cmul(u2, w2));
                            u3 = -cmul(u3, w1); }
        v[0*4+n1] = u0; v[1*4+n1] = u1; v[2*4+n1] = u2; v[3*4+n1] = u3;
    }
    #pragma unroll
    for (int r = 0; r < 4; ++r) {
        cf2 a0 = v[r*4+0], a1 = v[r*4+1], a2 = v[r*4+2], a3 = v[r*4+3];
        cf2 t0 = a0 + a2, t2 = a0 - a2;
        cf2 t1 = a1 + a3, t3 = rot90<SIGN>(a1 - a3);
        x[r]    = t0 + t1; x[r+4]  = t2 + t3;
        x[r+8]  = t0 - t1; x[r+12] = t2 - t3;
    }
}

template<int SIGN>
__device__ __forceinline__ void butterfly16(cf2* A, const int idx[16], cf2 w1) {
    cf2 x[16];
    #pragma unroll
    for (int n = 0; n < 16; ++n) x[n] = A[idx[n]];
    dft16<SIGN>(x);
    A[idx[0]] = x[0];
    A[idx[1]] = cmul(x[1], w1);
    const cf2 w2 = cmul(w1, w1);
    A[idx[2]] = cmul(x[2], w2);
    const cf2 w3 = cmul(w1, w2);
    A[idx[3]] = cmul(x[3], w3);
    const cf2 w4 = cmul(w2, w2);
    A[idx[4]] = cmul(x[4], w4);
    A[idx[5]] = cmul(x[5], cmul(w1, w4));
    A[idx[6]] = cmul(x[6], cmul(w2, w4));
    A[idx[7]] = cmul(x[7], cmul(w3, w4));
    const cf2 w8 = cmul(w4, w4);
    A[idx[8]]  = cmul(x[8],  w8);
    A[idx[9]]  = cmul(x[9],  cmul(w1, w8));
    A[idx[10]] = cmul(x[10], cmul(w2, w8));
    A[idx[11]] = cmul(x[11], cmul(w3, w8));
    const cf2 w12 = cmul(w4, w8);
    A[idx[12]] = cmul(x[12], w12);
    A[idx[13]] = cmul(x[13], cmul(w1, w12));
    A[idx[14]] = cmul(x[14], cmul(w2, w12));
    A[idx[15]] = cmul(x[15], cmul(w3, w12));
}

// ---------------- radix-8 pieces (fwd kernel) ----------------
template<int SIGN>
__device__ __forceinline__ void dft8(cf2 x[8]) {
    const cf2 w81 = { R2_F, SIGN * R2_F };
    const cf2 w83 = { -R2_F, SIGN * R2_F };
    cf2 u0 = x[0] + x[4], u1 = x[1] + x[5], u2 = x[2] + x[6], u3 = x[3] + x[7];
    cf2 v0 = x[0] - x[4];
    cf2 v1 = cmul(x[1] - x[5], w81);
    cf2 v2 = rot90<SIGN>(x[2] - x[6]);
    cf2 v3 = cmul(x[3] - x[7], w83);
    cf2 t0 = u0 + u2, t2 = u0 - u2;
    cf2 t1 = u1 + u3, t3 = rot90<SIGN>(u1 - u3);
    x[0] = t0 + t1; x[2] = t2 + t3; x[4] = t0 - t1; x[6] = t2 - t3;
    cf2 s0 = v0 + v2, s2 = v0 - v2;
    cf2 s1 = v1 + v3, s3 = rot90<SIGN>(v1 - v3);
    x[1] = s0 + s1; x[3] = s2 + s3; x[5] = s0 - s1; x[7] = s2 - s3;
}

template<int SIGN>
__device__ __forceinline__ void butterfly8(cf2* A, const int idx[8], cf2 w1) {
    cf2 x[8];
    #pragma unroll
    for (int n = 0; n < 8; ++n) x[n] = A[idx[n]];
    dft8<SIGN>(x);
    A[idx[0]] = x[0];
    A[idx[1]] = cmul(x[1], w1);
    const cf2 w2 = cmul(w1, w1);
    A[idx[2]] = cmul(x[2], w2);
    const cf2 w3 = cmul(w1, w2);
    A[idx[3]] = cmul(x[3], w3);
    const cf2 w4 = cmul(w2, w2);
    A[idx[4]] = cmul(x[4], w4);
    A[idx[5]] = cmul(x[5], cmul(w1, w4));
    A[idx[6]] = cmul(x[6], cmul(w2, w4));
    A[idx[7]] = cmul(x[7], cmul(w3, w4));
}

// ---------------------------------------------------------------------------
// Kernel 1: forward real FFT (length 16384) via 8192-pt complex FFT.
// Radix 8,8,8,8,2 ladder, 1024 threads. Blocks [NSIG, NSIG+16) build the
// twiddle table T via quadrant-reduced float sincos. W blocks (sig 64/65)
// write V(f) = conj(W(f)) * e^{-i pi k/8192}, k = 4094*f mod 16384.
// ---------------------------------------------------------------------------
__global__ __launch_bounds__(NTF, 4)
void fwd_fft_kernel(const float* __restrict__ xi, const float* __restrict__ w,
                    const float* __restrict__ tmpl, cf2* __restrict__ Tw,
                    cf2* __restrict__ spec) {
    __shared__ __attribute__((aligned(16))) cf2 A[M_LEN];   // 64 KB
    const int sig = blockIdx.x;
    const int tid = threadIdx.x;

    if (sig >= NSIG) {   // twiddle writer: T[k] = e^{-2 pi i k / 16384}
        const int k = (sig - NSIG) * NTF + tid;
        const int quad = k >> 12, mm = k & 4095;
        float s, c; __sincosf(PI_F * (float)mm / 8192.f, &s, &c);
        cf2 v;   // (cos th, -sin th), th = pi k/8192 = quad*pi/2 + t
        if      (quad == 0) v = (cf2){ c, -s};
        else if (quad == 1) v = (cf2){-s, -c};
        else if (quad == 2) v = (cf2){-c,  s};
        else                v = (cf2){ s,  c};
        Tw[k] = v;
        return;
    }

    const float* src;
    int nre;
    if (sig < 64)      { src = xi   + sig * L_LEN;         nre = L_LEN; }
    else if (sig < 66) { src = w    + (sig - 64) * L_LEN;  nre = L_LEN; }
    else               { src = tmpl + (sig - 66) * KT_LEN; nre = KT_LEN; }
    const bool isW = (sig >= 64 && sig < 66);
    const int nc = nre >> 1;
    const float4* s4 = (const float4*)src;
    const int g0 = tid ^ ((tid >> 4) & 15);
    #pragma unroll
    for (int m = 0; m < 4; ++m) {
        const int u = 2*tid + 2048*m;
        float4 vv = (u < nc) ? s4[tid + 1024*m] : make_float4(0.f, 0.f, 0.f, 0.f);
        ((float4*)A)[g0 + 1024*m] = vv;
    }
    __syncthreads();

    {   // stage 1: stride 1024, w1 = W_8192^tid
        int idx[8]; const int b0 = swz(tid);
        #pragma unroll
        for (int n = 0; n < 8; ++n) idx[n] = b0 + 1024*n;
        float sn, cs; __sincosf(-PI_F * (float)(2*tid) / 8192.f, &sn, &cs);
        butterfly8<-1>(A, idx, (cf2){cs, sn});
    }
    __syncthreads();
    {   // stage 2: stride 128, w1 = W_1024^j
        const int blk = tid >> 7, j = tid & 127, jb = blk*1024;
        const int jsw = j ^ (((j >> 5) & 3) << 1);
        int idx[8];
        #pragma unroll
        for (int n = 0; n < 8; ++n) idx[n] = jb + 128*n + (jsw ^ ((n & 3) << 3));
        float sn, cs; __sincosf(-PI_F * (float)(16*j) / 8192.f, &sn, &cs);
        butterfly8<-1>(A, idx, (cf2){cs, sn});
    }
    __syncthreads();
    {   // stage 3: stride 16, w1 = W_128^j
        const int blk = tid >> 4, j = tid & 15;
        const int base = blk*128 + j, bx = (blk & 3) << 3;
        int idx[8];
        #pragma unroll
        for (int n = 0; n < 8; ++n) idx[n] = (base + 16*n) ^ bx ^ ((n >> 1) << 1);
        float sn, cs; __sincosf(-PI_F * (float)(128*j) / 8192.f, &sn, &cs);
        butterfly8<-1>(A, idx, (cf2){cs, sn});
    }
    __syncthreads();
    {   // stage 4: stride 2, w1 = W_16^j (constant)
        const int blk = tid >> 1, j = tid & 1;
        const int Xa = ((blk >> 1) & 15) << 1;
        const int base = ((blk << 4) | j) ^ (Xa & 16);
        const int xv = Xa & 14;
        int idx[8];
        #pragma unroll
        for (int n = 0; n < 8; ++n) idx[n] = base + ((2*n) ^ xv);
        cf2 w1 = j ? (cf2){C8, -S8} : (cf2){1.f, 0.f};
        butterfly8<-1>(A, idx, w1);
    }
    __syncthreads();
    // Final radix-2 (stride 1, no twiddle), b128 in-place.
    #pragma unroll
    for (int m = 0; m < 4; ++m) {
        float4 pq = ((float4*)A)[g0 + 1024*m];
        ((float4*)A)[g0 + 1024*m] = make_float4(pq.x + pq.z, pq.y + pq.w,
                                                pq.x - pq.z, pq.y - pq.w);
    }
    __syncthreads();

    // Untangle packed result to real-signal spectrum X[f], f = 0..M.
    cf2* out = spec + (size_t)sig * SPEC_STRIDE;
    #pragma unroll
    for (int m = 0; m < 8; ++m) {
        const int f = tid + 1024*m;
        const int fb = (M_LEN - f) & (M_LEN - 1);
        cf2 Za = A[swz(pos8(f))];
        cf2 Zb = A[swz(pos8(fb))];
        cf2 E = (cf2){0.5f*(Za.x + Zb.x), 0.5f*(Za.y - Zb.y)};
        cf2 D = (cf2){Za.x - Zb.x, Za.y + Zb.y};
        cf2 O = (cf2){0.5f*D.y, -0.5f*D.x};
        float sn, cs;
        __sincosf(-PI_F * (float)f / 8192.f, &sn, &cs);
        cf2 val = E + (cf2){cs*O.x - sn*O.y, cs*O.y + sn*O.x};
        if (isW) {   // V(f) = conj(W(f)) * e^{-i pi k/8192}, k exact int mod
            const int k = (4094 * f) & (L_LEN - 1);
            float psn, pcs; __sincosf(-PI_F * (float)k / 8192.f, &psn, &pcs);
            val = cmul((cf2){val.x, -val.y}, (cf2){pcs, psn});
        }
        out[f] = val;
    }
    if (tid == 0) {   // f = 8192
        cf2 Za = A[swz(0)];
        cf2 val = (cf2){Za.x - Za.y, 0.f};
        if (isW) {   // k(8192) = 8192 -> phase = (-1, 0)
            val = (cf2){-val.x, 0.f};
        }
        out[M_LEN] = val;
    }
}

// ---------------------------------------------------------------------------
// Kernel 1b (R16): XV[f] = X[f]*V[f], in-place into X's spec slots.
// One block per (b,c); V slots (64/65) read-only; no cross-block hazard.
// Removes the 50x-redundant X*V from inv and 1/3 of its L2 traffic.
// ---------------------------------------------------------------------------
__global__ __launch_bounds__(1024)
void xv_kernel(cf2* __restrict__ spec) {
    const int bc = blockIdx.x;          // 0..63 = b*2 + c
    cf2* Xs = spec + (size_t)bc * SPEC_STRIDE;
    const cf2* Vs = spec + (size_t)(64 + (bc & 1)) * SPEC_STRIDE;
    const int tid = threadIdx.x;
    float4* X4 = (float4*)Xs;
    const float4* V4 = (const float4*)Vs;
    #pragma unroll
    for (int m = 0; m < 4; ++m) {
        const int p = tid + 1024*m;     // float4 pair index < 4096
        float4 xv = X4[p], vv = V4[p];
        cf2 a = cmul((cf2){xv.x, xv.y}, (cf2){vv.x, vv.y});
        cf2 b = cmul((cf2){xv.z, xv.w}, (cf2){vv.z, vv.w});
        X4[p] = make_float4(a.x, a.y, b.x, b.y);
    }
    if (tid == 0) Xs[M_LEN] = cmul(Xs[M_LEN], Vs[M_LEN]);
}

// ---------------------------------------------------------------------------
// Kernel 2 (R15+R16): product (XV * conj(H)) + Hermitian pack + FIRST radix-2
// stage fused in registers (in-thread; no cross-lane). Then 16,16,16 stages
// on the two 4096-halves; stride-1 last stage (twiddle = 1) is read-only+max.
// Z' carries 2x (0.5 dropped) -> divide by 2*M*hh.
// ---------------------------------------------------------------------------
__global__ __launch_bounds__(NTI, 4)
void inv_fft_kernel(const cf2* __restrict__ spec, const cf2* __restrict__ T,
                    const float* __restrict__ hh, float* __restrict__ zarr) {
    __shared__ __attribute__((aligned(16))) cf2 A[M_LEN];   // 64 KB
    const int idx0 = blockIdx.x;
    const int c = idx0 & 1;
    const int n = (idx0 >> 1) % NTPL;
    const int b = idx0 / (2 * NTPL);
    const int tid = threadIdx.x;

    const cf2* Xs = spec + (size_t)(b*2 + c)      * SPEC_STRIDE;   // = XV
    const cf2* Hs = spec + (size_t)(66 + n*2 + c) * SPEC_STRIDE;
    const float4* X4 = (const float4*)Xs;
    const float4* H4 = (const float4*)Hs;
    const float4* T4 = (const float4*)T;

    // Phase 1: per t' = tid + 512m, pair f0 = 2t', f1 = 2t'+1.
    // 4-group per f: products at f, 4096-f, 4096+f, 8192-f ->
    // Z'[f], Z'[8192-f] (compose at u=f, twiddle T[f]) and
    // Z'[4096-f], Z'[4096+f] (compose at u=4096-f, twiddle -i*conj(T[f])).
    // Radix-2: (Z'[f], Z'[4096+f]) with conj(T[2f]); (Z'[4096-f], Z'[8192-f])
    // with -T[2f].  ytop -> A[0,4096), ybot -> A[4096,8192), swizzled.
    #pragma unroll
    for (int m = 0; m < 2; ++m) {
        const int tp = tid + 512*m;
        const int f0 = 2*tp, f1 = f0 + 1;
        float4 xa = X4[tp],        ha = H4[tp];
        float4 xq = X4[tp + 2048], hq = H4[tp + 2048];
        cf2 PA0 = cmulc((cf2){xa.x, xa.y}, (cf2){ha.x, ha.y});
        cf2 PA1 = cmulc((cf2){xa.z, xa.w}, (cf2){ha.z, ha.w});
        cf2 QB0 = cmulc((cf2){xq.x, xq.y}, (cf2){hq.x, hq.y});
        cf2 QB1 = cmulc((cf2){xq.z, xq.w}, (cf2){hq.z, hq.w});
        cf2 PB0 = cmulc(Xs[4096 - f0], Hs[4096 - f0]);
        cf2 PB1 = cmulc(Xs[4096 - f1], Hs[4096 - f1]);
        cf2 QA0 = cmulc(Xs[8192 - f0], Hs[8192 - f0]);
        cf2 QA1 = cmulc(Xs[8192 - f1], Hs[8192 - f1]);
        float4 tf4 = T4[tp];            // T[f0], T[f1]
        float4 t2a = T4[2*tp];          // T[2f0] in .xy
        float4 t2b = T4[2*tp + 1];      // T[2f1] in .xy
        cf2 Tf0 = (cf2){tf4.x, tf4.y}, Tf1 = (cf2){tf4.z, tf4.w};
        cf2 T20 = (cf2){t2a.x, t2a.y}, T21 = (cf2){t2b.x, t2b.y};
        // --- f0 ---
        cf2 SpA0 = pk_addch(PA0, QA0), SmA0 = pk_subcl(PA0, QA0);
        cf2 RA0 = cmulca(Tf0, SmA0);
        cf2 ZA1_0 = pk_compose1(SpA0, RA0);     // Z'[f0]
        cf2 ZA2_0 = pk_compose2(SpA0, RA0);     // Z'[8192-f0]
        cf2 tB0 = (cf2){-Tf0.y, -Tf0.x};        // T[4096-f0]
        cf2 SpB0 = pk_addch(PB0, QB0), SmB0 = pk_subcl(PB0, QB0);
        cf2 RB0 = cmulca(tB0, SmB0);
        cf2 ZB1_0 = pk_compose1(SpB0, RB0);     // Z'[4096-f0]
        cf2 ZB2_0 = pk_compose2(SpB0, RB0);     // Z'[4096+f0]
        cf2 top0 = ZA1_0 + ZB2_0;
        cf2 bot0 = cmulca(T20, ZA1_0 - ZB2_0);
        // --- f1 ---
        cf2 SpA1 = pk_addch(PA1, QA1), SmA1 = pk_subcl(PA1, QA1);
        cf2 RA1 = cmulca(Tf1, SmA1);
        cf2 ZA1_1 = pk_compose1(SpA1, RA1);
        cf2 ZA2_1 = pk_compose2(SpA1, RA1);
        cf2 tB1 = (cf2){-Tf1.y, -Tf1.x};
        cf2 SpB1 = pk_addch(PB1, QB1), SmB1 = pk_subcl(PB1, QB1);
        cf2 RB1 = cmulca(tB1, SmB1);
        cf2 ZB1_1 = pk_compose1(SpB1, RB1);
        cf2 ZB2_1 = pk_compose2(SpB1, RB1);
        cf2 top1 = ZA1_1 + ZB2_1;
        cf2 bot1 = cmulca(T21, ZA1_1 - ZB2_1);
        // coalesced swizzled float4 writes for the fwd side
        const int gt = tp ^ ((tp >> 4) & 15);
        ((float4*)A)[gt]        = make_float4(top0.x, top0.y, top1.x, top1.y);
        ((float4*)A)[2048 + gt] = make_float4(bot0.x, bot0.y, bot1.x, bot1.y);
        // rev-side butterflies (skip f0 == 0: its pair (4096,8192) is invalid;
        // the fwd butterfly above already used the correct self-paired Z'[4096])
        if (tp > 0) {
            cf2 tr0 = ZB1_0 + ZA2_0;
            cf2 dr0 = cmul(ZB1_0 - ZA2_0, T20);
            A[swz(4096 - f0)] = tr0;
            A[swz(8192 - f0)] = -dr0;
        }
        cf2 tr1 = ZB1_1 + ZA2_1;
        cf2 dr1 = cmul(ZB1_1 - ZA2_1, T21);
        A[swz(4096 - f1)] = tr1;
        A[swz(8192 - f1)] = -dr1;
    }
    if (tid == 0) {   // f = 2048 butterfly (2048, 6144), Wi^2048 = +i
        cf2 P = cmulc(Xs[2048], Hs[2048]);
        cf2 Q = cmulc(Xs[6144], Hs[6144]);
        cf2 Tc = (cf2){R2_F, -R2_F};           // T[2048]
        cf2 Sp = pk_addch(P, Q), Sm = pk_subcl(P, Q);
        cf2 R = cmulca(Tc, Sm);
        cf2 Z1 = pk_compose1(Sp, R), Z2 = pk_compose2(Sp, R);
        cf2 d = Z1 - Z2;
        A[swz(2048)] = Z1 + Z2;
        A[swz(6144)] = (cf2){-d.y, d.x};
    }
    __syncthreads();

    {   // stage 1 of the 4096-halves: stride 256, w1 = conj(T[4j])
        const int h = tid >> 8, j = tid & 255;
        const int Hb = h << 12;
        const int jx = j ^ (((j >> 5) & 7) << 1);
        int idx[16];
        #pragma unroll
        for (int nn = 0; nn < 16; ++nn)
            idx[nn] = Hb + 256*nn + (jx ^ ((nn & 1) << 4));
        butterfly16<+1>(A, idx, ldT<+1>(T, 4*j));
    }
    __syncthreads();
    {   // stage 2: stride 16, w1 = conj(T[64j])
        const int h = tid >> 8, q = (tid >> 4) & 15, j = tid & 15;
        const int base = (h << 12) + (q << 8);
        const int qb = q & 1;
        int idx[16];
        #pragma unroll
        for (int nn = 0; nn < 16; ++nn)
            idx[nn] = base + 16*(nn ^ qb) + (j ^ (((nn >> 1) & 7) << 1));
        butterfly16<+1>(A, idx, ldT<+1>(T, 64*j));
    }
    __syncthreads();

    // stage 3: stride 1, twiddle = W_16^0 = 1 -> read-only dft16 + max.
    float mx = -INFINITY;
    {
        const int bb = 16 * (tid ^ ((tid >> 4) & 1));
        const int m3 = ((tid >> 1) & 7) << 1;
        cf2 x[16];
        #pragma unroll
        for (int e = 0; e < 8; ++e) {
            float4 v = ((const float4*)A)[(bb + ((2*e) ^ m3)) >> 1];
            x[2*e]     = (cf2){v.x, v.y};
            x[2*e + 1] = (cf2){v.z, v.w};
        }
        dft16<+1>(x);
        #pragma unroll
        for (int nn = 0; nn < 16; ++nn)
            mx = fmaxf(mx, fmaxf(x[nn].x, x[nn].y));
    }
    __syncthreads();   // all stage-3 reads done before reusing A as scratch
    for (int off = 32; off > 0; off >>= 1)
        mx = fmaxf(mx, __shfl_xor(mx, off));
    const int lane = tid & 63, wv = tid >> 6;   // 8 waves
    float* redf = (float*)A;
    if (lane == 0) redf[wv] = mx;
    __syncthreads();
    if (tid == 0) {
        float mm = redf[0];
        for (int i = 1; i < NTI/64; ++i) mm = fmaxf(mm, redf[i]);
        zarr[(b*2 + c)*NTPL + n] = mm / (2.f * (float)M_LEN * hh[n*2 + c]);
    }
}

// ---------------------------------------------------------------------------
// Kernel 3: tiny CNN/MLP head. One block per batch element.
// R12: all weights staged in LDS (coalesced), all MAC loops unrolled over
// LDS reads, fc1 parallelized 32 outputs x 8 lanes + shfl_xor tree.
// ---------------------------------------------------------------------------
#define W1_OFF 0        // 16x6 = 96
#define B1_OFF 96       // 16
#define W2_OFF 112      // 32x48 = 1536
#define B2_OFF 1648     // 32
#define W3_OFF 1680     // 32x132 (padded from 128) = 4224
#define B3_OFF 5904     // 32
#define W4_OFF 5936     // 2x32 = 64
#define B4_OFF 6000     // 2
#define WSM_SZ 6002

__global__ __launch_bounds__(256)
void head_kernel(const float* __restrict__ zarr,
                 const float* __restrict__ W1, const float* __restrict__ b1,
                 const float* __restrict__ W2, const float* __restrict__ b2,
                 const float* __restrict__ W3, const float* __restrict__ b3,
                 const float* __restrict__ W4, const float* __restrict__ b4,
                 float* __restrict__ out) {
    __shared__ float wsm[WSM_SZ];
    __shared__ float zl[2*NTPL];
    __shared__ float s1[16*48];
    __shared__ float p1[16*16];
    __shared__ float s2[32*14];
    __shared__ float hflat[128];
    __shared__ float h1[32];
    const int b = blockIdx.x, tid = threadIdx.x;

    for (int i = tid; i < 96;   i += 256) wsm[W1_OFF + i] = W1[i];
    if (tid < 16)                         wsm[B1_OFF + tid] = b1[tid];
    for (int i = tid; i < 1536; i += 256) wsm[W2_OFF + i] = W2[i];
    if (tid < 32)                         wsm[B2_OFF + tid] = b2[tid];
    for (int i = tid; i < 4096; i += 256)
        wsm[W3_OFF + (i >> 7)*132 + (i & 127)] = W3[i];
    if (tid < 32)                         wsm[B3_OFF + tid] = b3[tid];
    if (tid < 64)                         wsm[W4_OFF + tid] = W4[tid];
    if (tid < 2)                          wsm[B4_OFF + tid] = b4[tid];
    for (int i = tid; i < 2*NTPL; i += 256) zl[i] = zarr[b*2*NTPL + i];
    __syncthreads();

    for (int i = tid; i < 16*48; i += 256) {
        const int o = i / 48, t = i % 48;
        float acc = wsm[B1_OFF + o];
        #pragma unroll
        for (int cc = 0; cc < 2; ++cc)
            #pragma unroll
            for (int k = 0; k < 3; ++k)
                acc += zl[cc*NTPL + t + k] * wsm[W1_OFF + o*6 + cc*3 + k];
        s1[i] = 1.f / (1.f + __expf(-acc));
    }
    __syncthreads();
    for (int i = tid; i < 16*16; i += 256) {
        const int o = i / 16, u = i % 16;
        p1[i] = fmaxf(fmaxf(s1[o*48 + 3*u], s1[o*48 + 3*u+1]), s1[o*48 + 3*u+2]);
    }
    __syncthreads();
    for (int i = tid; i < 32*14; i += 256) {
        const int o = i / 14, t = i % 14;
        float acc = wsm[B2_OFF + o];
        #pragma unroll
        for (int cc = 0; cc < 16; ++cc)
            #pragma unroll
            for (int k = 0; k < 3; ++k)
                acc += p1[cc*16 + t + k] * wsm[W2_OFF + o*48 + cc*3 + k];
        s2[o*14 + t] = 1.f / (1.f + __expf(-acc));
    }
    __syncthreads();
    for (int i = tid; i < 128; i += 256) {
        const int o = i / 4, u = i % 4;
        hflat[i] = fmaxf(fmaxf(s2[o*14 + 3*u], s2[o*14 + 3*u+1]), s2[o*14 + 3*u+2]);
    }
    __syncthreads();
    {
        const int o = tid >> 3, lg = tid & 7;
        float acc = 0.f;
        #pragma unroll
        for (int k = 0; k < 16; ++k)
            acc += hflat[lg + 8*k] * wsm[W3_OFF + o*132 + lg + 8*k];
        acc += __shfl_xor(acc, 1);
        acc += __shfl_xor(acc, 2);
        acc += __shfl_xor(acc, 4);
        if (lg == 0) h1[o] = fmaxf(acc + wsm[B3_OFF + o], 0.f);
    }
    __syncthreads();
    if (tid < 64) {
        const int o = tid >> 5, j = tid & 31;
        float p = h1[j] * wsm[W4_OFF + o*32 + j];
        p += __shfl_xor(p, 1);
        p += __shfl_xor(p, 2);
        p += __shfl_xor(p, 4);
        p += __shfl_xor(p, 8);
        p += __shfl_xor(p, 16);
        if (j == 0) out[b*2 + o] = p + wsm[B4_OFF + o];
    }
}

extern "C" void kernel_launch(void* const* d_in, const int* in_sizes, int n_in,
                              void* d_out, int out_size, void* d_ws, size_t ws_size,
                              hipStream_t stream) {
    const float* xi   = (const float*)d_in[0];
    const float* Sw   = (const float*)d_in[1];
    const float* tmpl = (const float*)d_in[2];
    const float* hh   = (const float*)d_in[3];
    const float* W1   = (const float*)d_in[4];
    const float* b1   = (const float*)d_in[5];
    const float* W2   = (const float*)d_in[6];
    const float* b2   = (const float*)d_in[7];
    const float* W3   = (const float*)d_in[8];
    const float* b3   = (const float*)d_in[9];
    const float* W4   = (const float*)d_in[10];
    const float* b4   = (const float*)d_in[11];
    float* out = (float*)d_out;

    cf2* T16  = (cf2*)d_ws;                         // 16384 cf2 = 128 KB
    cf2* spec = T16 + 16384;                        // NSIG * SPEC_STRIDE cf2
    float* zarr = (float*)(spec + (size_t)NSIG * SPEC_STRIDE);

    fwd_fft_kernel<<<dim3(NSIG + 16), dim3(NTF), 0, stream>>>(xi, Sw, tmpl, T16, spec);
    xv_kernel<<<dim3(64), dim3(1024), 0, stream>>>(spec);
    inv_fft_kernel<<<dim3(BB * NTPL * 2), dim3(NTI), 0, stream>>>(spec, T16, hh, zarr);
    head_kernel<<<dim3(BB), dim3(256), 0, stream>>>(zarr, W1, b1, W2, b2, W3, b3, W4, b4, out);
}